// Round 8
// baseline (294.875 us; speedup 1.0000x reference)
//
#include <hip/hip_runtime.h>

#define N_PTS 32768
#define BATCH 16
#define PIO2F 1.5707963705062866f

// ---------------- repetition macros ----------------
#define REP16(M) M(0)M(1)M(2)M(3)M(4)M(5)M(6)M(7)M(8)M(9)M(10)M(11)M(12)M(13)M(14)M(15)
#define REP16I(M) M(0)M(1)M(2)M(3)M(4)M(5)M(6)M(7)M(8)M(9)M(10)M(11)M(12)M(13)M(14)M(15)
#define REP62(M) M(0)M(1)M(2)M(3)M(4)M(5)M(6)M(7)M(8)M(9)M(10)M(11)M(12)M(13)M(14)M(15)\
M(16)M(17)M(18)M(19)M(20)M(21)M(22)M(23)M(24)M(25)M(26)M(27)M(28)M(29)M(30)M(31)\
M(32)M(33)M(34)M(35)M(36)M(37)M(38)M(39)M(40)M(41)M(42)M(43)M(44)M(45)M(46)M(47)\
M(48)M(49)M(50)M(51)M(52)M(53)M(54)M(55)M(56)M(57)M(58)M(59)M(60)M(61)

#define PE(sc, ia, ib, ic, id) { float a0 = x0 * sc, a1 = x1 * sc; \
    h_##ia = sinf(a0); h_##ib = sinf(a1); \
    h_##ic = sinf(a0 + PIO2F); h_##id = sinf(a1 + PIO2F); }
#define POSENC_BODY \
    h_0 = x0; h_1 = x1; \
    PE(1.f,2,3,32,33)      PE(2.f,4,5,34,35)      PE(4.f,6,7,36,37) \
    PE(8.f,8,9,38,39)      PE(16.f,10,11,40,41)   PE(32.f,12,13,42,43) \
    PE(64.f,14,15,44,45)   PE(128.f,16,17,46,47)  PE(256.f,18,19,48,49) \
    PE(512.f,20,21,50,51)  PE(1024.f,22,23,52,53) PE(2048.f,24,25,54,55) \
    PE(4096.f,26,27,56,57) PE(8192.f,28,29,58,59) PE(16384.f,30,31,60,61)

#define HYPER_BODY \
    REP16(L0) \
    REP16(L1) \
    REP16(L2) \
    REP16(L3)

// ---------------- types / helpers ----------------
typedef __attribute__((ext_vector_type(8))) short short8;
typedef __attribute__((ext_vector_type(4))) float f32x4;

union S8u { short8 v; unsigned u[4]; };

__device__ __forceinline__ float silu_f(float v) {
    return v * __builtin_amdgcn_rcpf(1.0f + __expf(-v));
}

__device__ __forceinline__ float wave_sum(float v) {
    #pragma unroll
    for (int off = 1; off < 64; off <<= 1) v += __shfl_xor(v, off, 64);
    return v;
}

__device__ __forceinline__ void bfsplit2(float a, float b, unsigned& hi, unsigned& lo) {
    unsigned ua = __float_as_uint(a), ub = __float_as_uint(b);
    hi = (ua >> 16) | (ub & 0xffff0000u);
    float ra = a - __uint_as_float(ua & 0xffff0000u);
    float rb = b - __uint_as_float(ub & 0xffff0000u);
    lo = (__float_as_uint(ra) >> 16) | (__float_as_uint(rb) & 0xffff0000u);
}

__device__ __forceinline__ f32x4 mfma16(short8 a, short8 b, f32x4 c) {
    return __builtin_amdgcn_mfma_f32_16x16x32_bf16(a, b, c, 0, 0, 0);
}

__device__ __forceinline__ short8 s8zero() {
    S8u t; t.u[0] = 0; t.u[1] = 0; t.u[2] = 0; t.u[3] = 0; return t.v;
}

__device__ __forceinline__ void packfrag(f32x4 f0, f32x4 f1, short8& h, short8& l) {
    S8u th, tl;
    bfsplit2(f0[0], f0[1], th.u[0], tl.u[0]);
    bfsplit2(f0[2], f0[3], th.u[1], tl.u[1]);
    bfsplit2(f1[0], f1[1], th.u[2], tl.u[2]);
    bfsplit2(f1[2], f1[3], th.u[3], tl.u[3]);
    h = th.v; l = tl.v;
}

// ---------------- kernel 2: hyper-weights wv ----------------
__global__ void wv_kernel(
    const float* __restrict__ latent,
    const float* __restrict__ pw0, const float* __restrict__ pb0,
    const float* __restrict__ lnw0, const float* __restrict__ lnb0,
    const float* __restrict__ pw1, const float* __restrict__ pb1,
    const float* __restrict__ lnw1, const float* __restrict__ lnb1,
    const float* __restrict__ pw2, const float* __restrict__ pb2,
    const float* __restrict__ lnw2, const float* __restrict__ lnb2,
    const float* __restrict__ pw3, const float* __restrict__ pb3,
    const float* __restrict__ lnw3, const float* __restrict__ lnb3,
    float* __restrict__ wvb) {
    int blk = blockIdx.x;
    int l = blk >> 8;
    int rest = blk & 255;
    int b = rest >> 4, o = rest & 15;
    int c = threadIdx.x;

    const float *pw, *pb, *lnw, *lnb;
    float* outp;
    int ch;
    switch (l) {
        case 0:  pw = pw0; pb = pb0; lnw = lnw0; lnb = lnb0; outp = wvb;                 ch = 62; break;
        case 1:  pw = pw1; pb = pb1; lnw = lnw1; lnb = lnb1; outp = wvb + 15872;         ch = 16; break;
        case 2:  pw = pw2; pb = pb2; lnw = lnw2; lnb = lnb2; outp = wvb + 15872 + 4096;  ch = 16; break;
        default: pw = pw3; pb = pb3; lnw = lnw3; lnb = lnb3; outp = wvb + 15872 + 8192;  ch = 16; break;
    }
    const float* lat = latent + ((size_t)(b * 64 + l * 16 + o)) * 64;
    float dot = 0.f;
    if (c < ch) {
        const float* pr = pw + ((size_t)(o * ch + c)) * 64;
        #pragma unroll
        for (int d0 = 0; d0 < 64; d0++) dot += lat[d0] * pr[d0];
    }
    float act = (c < ch) ? dot : 0.f;
    float mu = wave_sum(act) * (1.0f / ch);
    float diff = (c < ch) ? (dot - mu) : 0.f;
    float var = wave_sum(diff * diff) * (1.0f / ch);
    float norm = diff * rsqrtf(var + 1e-5f);
    if (c < ch) outp[(size_t)(b * 16 + o) * ch + c] = norm * lnw[c] + lnb[c] + pb[o * ch + c];
}

// ---------------- hyper layer macros (shared with fused fallback) ----------------
#define L0T(i) acc += h_##i * wptr[i];
#define LAT(i) acc += ha_##i * wptr[i];
#define LBT(i) acc += hb_##i * wptr[i];
#define L0(o) { const float* wptr = wv0 + (o) * 62; float acc = mb0[o]; REP62(L0T) ha_##o = silu_f(acc); }
#define L1(o) { const float* wptr = wv1 + (o) * 16; float acc = mb1[o]; REP16I(LAT) hb_##o = silu_f(acc); }
#define L2(o) { const float* wptr = wv2 + (o) * 16; float acc = mb2[o]; REP16I(LBT) ha_##o = silu_f(acc); }
#define L3(o) { const float* wptr = wv3 + (o) * 16; float acc = mb3[o]; REP16I(LAT) hb_##o = silu_f(acc); }

// ---------------- kernel A: posenc + hyper layers, CHUNKED layer-0 ----------------
// Layer-0 consumes posenc features as they are produced: 16 accumulators stay
// live, each scale-chunk produces 4 features then 64 FMAs. Peak live set ~30
// floats -> structurally spill-proof at any occupancy.
__global__ __launch_bounds__(256, 4) void hyper_kernel(
    const float* __restrict__ x, const float* __restrict__ wvb,
    const float* __restrict__ mb0, const float* __restrict__ mb1,
    const float* __restrict__ mb2, const float* __restrict__ mb3,
    float* __restrict__ hbg) {
    const int b = blockIdx.x >> 7;
    const int p = ((blockIdx.x & 127) << 8) | threadIdx.x;

    const float x0 = x[2 * p], x1 = x[2 * p + 1];

    const float* wv0 = wvb + b * 992;
    const float* wv1 = wvb + 15872 + b * 256;
    const float* wv2 = wvb + 15872 + 4096 + b * 256;
    const float* wv3 = wvb + 15872 + 8192 + b * 256;

    // ---- layer 0, chunked ----
#define DACC(o) float acc_##o = mb0[o];
    REP16(DACC)
#undef DACC
    // x-terms (features 0,1)
#define AX(o) acc_##o = fmaf(x0, wv0[(o) * 62 + 0], acc_##o); \
              acc_##o = fmaf(x1, wv0[(o) * 62 + 1], acc_##o);
    REP16(AX)
#undef AX
    // scale-chunks: features 2+2s, 3+2s, 32+2s, 33+2s
#define AQ(o) acc_##o = fmaf(s0, wp[(o) * 62 +  0], acc_##o); \
              acc_##o = fmaf(s1, wp[(o) * 62 +  1], acc_##o); \
              acc_##o = fmaf(c0, wp[(o) * 62 + 30], acc_##o); \
              acc_##o = fmaf(c1, wp[(o) * 62 + 31], acc_##o);
#define SCHUNK(sc, sidx) { \
    float a0 = x0 * sc, a1 = x1 * sc; \
    float s0 = sinf(a0), s1 = sinf(a1); \
    float c0 = sinf(a0 + PIO2F), c1 = sinf(a1 + PIO2F); \
    const float* wp = wv0 + 2 + 2 * (sidx); \
    REP16(AQ) }
    SCHUNK(1.f, 0)      SCHUNK(2.f, 1)      SCHUNK(4.f, 2)
    SCHUNK(8.f, 3)      SCHUNK(16.f, 4)     SCHUNK(32.f, 5)
    SCHUNK(64.f, 6)     SCHUNK(128.f, 7)    SCHUNK(256.f, 8)
    SCHUNK(512.f, 9)    SCHUNK(1024.f, 10)  SCHUNK(2048.f, 11)
    SCHUNK(4096.f, 12)  SCHUNK(8192.f, 13)  SCHUNK(16384.f, 14)
#undef SCHUNK
#undef AQ

#define DHA(i) float ha_##i;
    REP16(DHA)
#undef DHA
#define FIN0(o) ha_##o = silu_f(acc_##o);
    REP16(FIN0)
#undef FIN0

#define DHB(i) float hb_##i;
    REP16(DHB)
#undef DHB
    // layers 1-3 (small live sets)
    REP16(L1)
    REP16(L2)
    REP16(L3)

#define SB(i) hbg[((size_t)(b * 16 + (i)) << 15) | p] = hb_##i;
    REP16(SB)
#undef SB
}

// ---------------- LDS layout for mfma_kernel (bytes) ----------------
#define MB_BOUNCE_OFF 0            // f32 8 x [16][108]  55296
#define MB_W2H_OFF    55296        // short [112][104]   23296
#define MB_W2L_OFF    78592        // short [112][104]   23296
#define MB_W1H_OFF    101888       // short [112][24]     5376
#define MB_W1L_OFF    107264       // short [112][24]     5376
#define MB_B1_OFF     112640       // f32 [112]            448
#define MB_B2_OFF     113088
#define MB_W3_OFF     113536
#define MB_LDS_TOTAL  113984

// ---------------- kernel B: shared MLP on MFMA ----------------
__global__ __launch_bounds__(512, 2) void mfma_kernel(
    const float* __restrict__ hbg,
    const float* __restrict__ w1, const float* __restrict__ b1,
    const float* __restrict__ w2, const float* __restrict__ b2,
    const float* __restrict__ w3, const float* __restrict__ b3,
    float* __restrict__ out) {
    extern __shared__ char smem[];
    float* lds_bounce = (float*)(smem + MB_BOUNCE_OFF);
    short* lds_w2h    = (short*)(smem + MB_W2H_OFF);
    short* lds_w2l    = (short*)(smem + MB_W2L_OFF);
    short* lds_w1h    = (short*)(smem + MB_W1H_OFF);
    short* lds_w1l    = (short*)(smem + MB_W1L_OFF);
    float* lds_b1     = (float*)(smem + MB_B1_OFF);
    float* lds_b2     = (float*)(smem + MB_B2_OFF);
    float* lds_w3     = (float*)(smem + MB_W3_OFF);

    const int b  = blockIdx.x >> 6;
    const int p0 = (blockIdx.x & 63) * 512;

    for (int idx = threadIdx.x; idx < 112 * 104; idx += 512) {
        int o = idx / 104, k = idx - o * 104;
        float v = (o < 100 && k < 100) ? w2[o * 100 + k] : 0.f;
        unsigned ua = __float_as_uint(v);
        float rv = v - __uint_as_float(ua & 0xffff0000u);
        lds_w2h[idx] = (short)(ua >> 16);
        lds_w2l[idx] = (short)(__float_as_uint(rv) >> 16);
    }
    for (int idx = threadIdx.x; idx < 112 * 24; idx += 512) {
        int o = idx / 24, k = idx - o * 24;
        float v = (o < 100 && k < 16) ? w1[o * 16 + k] : 0.f;
        unsigned ua = __float_as_uint(v);
        float rv = v - __uint_as_float(ua & 0xffff0000u);
        lds_w1h[idx] = (short)(ua >> 16);
        lds_w1l[idx] = (short)(__float_as_uint(rv) >> 16);
    }
    if (threadIdx.x < 112) {
        int o = threadIdx.x;
        lds_b1[o] = (o < 100) ? b1[o] : 0.f;
        lds_b2[o] = (o < 100) ? b2[o] : 0.f;
        lds_w3[o] = (o < 100) ? w3[o] : 0.f;
    }
    __syncthreads();

    const int l    = threadIdx.x & 63;
    const int w    = threadIdx.x >> 6;
    const int lrow = l & 15;
    const int lkg  = l >> 4;
    float* bounce = lds_bounce + w * (16 * 108);
    const int pbase = w * 64;
    const float b3v = b3[0];
    const f32x4 FZ = {0.f, 0.f, 0.f, 0.f};

    short8 hbh[4], hbl[4];
    #pragma unroll
    for (int pt = 0; pt < 4; ++pt) {
        const size_t pcol = (size_t)(p0 + pbase + pt * 16 + lrow);
        const int f0i = 8 * (lkg & 1);
        float fv[8];
        #pragma unroll
        for (int j = 0; j < 8; ++j)
            fv[j] = hbg[((size_t)(b * 16 + f0i + j) << 15) | pcol];
        f32x4 f0 = {fv[0], fv[1], fv[2], fv[3]};
        f32x4 f1 = {fv[4], fv[5], fv[6], fv[7]};
        if (lkg >= 2) { f0 = FZ; f1 = FZ; }
        packfrag(f0, f1, hbh[pt], hbl[pt]);
    }

    float outp_[4];
    #pragma unroll
    for (int pt = 0; pt < 4; ++pt) outp_[pt] = 0.f;

    short8 h2h[4][4], h2l[4][4];
    #pragma unroll
    for (int pt = 0; pt < 4; ++pt) {
        #pragma unroll
        for (int fmt = 0; fmt < 7; ++fmt) {
            f32x4 acc;
            #pragma unroll
            for (int r = 0; r < 4; ++r) acc[r] = lds_b1[fmt * 16 + lkg * 4 + r];
            short8 ah = *(const short8*)(lds_w1h + (fmt * 16 + lrow) * 24 + (lkg & 1) * 8);
            short8 al = *(const short8*)(lds_w1l + (fmt * 16 + lrow) * 24 + (lkg & 1) * 8);
            if (lkg >= 2) { ah = s8zero(); al = s8zero(); }
            acc = mfma16(ah, hbh[pt], acc);
            acc = mfma16(ah, hbl[pt], acc);
            acc = mfma16(al, hbh[pt], acc);
            f32x4 sv;
            #pragma unroll
            for (int r = 0; r < 4; ++r) sv[r] = silu_f(acc[r]);
            if (!(fmt == 6 && lkg == 3))
                *(f32x4*)(bounce + lrow * 108 + fmt * 16 + lkg * 4) = sv;
        }
        #pragma unroll
        for (int ks = 0; ks < 4; ++ks) {
            int kb = ks * 32 + lkg * 8;
            bool act = kb < 104;
            int kba = act ? kb : 0;
            const float* s2 = bounce + lrow * 108 + kba;
            f32x4 f0 = *(const f32x4*)s2;
            f32x4 f1 = *(const f32x4*)(s2 + 4);
            if (!act) { f0 = FZ; f1 = FZ; }
            packfrag(f0, f1, h2h[pt][ks], h2l[pt][ks]);
        }
    }

    #pragma unroll
    for (int fmt = 0; fmt < 7; ++fmt) {
        float bi[4], w3r[4];
        #pragma unroll
        for (int r = 0; r < 4; ++r) {
            bi[r]  = lds_b2[fmt * 16 + lkg * 4 + r];
            w3r[r] = lds_w3[fmt * 16 + lkg * 4 + r];
        }
        f32x4 acc[4];
        #pragma unroll
        for (int pt = 0; pt < 4; ++pt) { f32x4 t = {bi[0], bi[1], bi[2], bi[3]}; acc[pt] = t; }
        #pragma unroll
        for (int ks = 0; ks < 4; ++ks) {
            int kb = ks * 32 + lkg * 8;
            bool act = kb < 104;
            int kba = act ? kb : 0;
            short8 ah = *(const short8*)(lds_w2h + (fmt * 16 + lrow) * 104 + kba);
            short8 al = *(const short8*)(lds_w2l + (fmt * 16 + lrow) * 104 + kba);
            if (!act) { ah = s8zero(); al = s8zero(); }
            #pragma unroll
            for (int pt = 0; pt < 4; ++pt) {
                acc[pt] = mfma16(ah, h2h[pt][ks], acc[pt]);
                acc[pt] = mfma16(ah, h2l[pt][ks], acc[pt]);
                acc[pt] = mfma16(al, h2h[pt][ks], acc[pt]);
            }
        }
        #pragma unroll
        for (int pt = 0; pt < 4; ++pt) {
            #pragma unroll
            for (int r = 0; r < 4; ++r)
                outp_[pt] = fmaf(silu_f(acc[pt][r]), w3r[r], outp_[pt]);
        }
    }

    float vred[4];
    #pragma unroll
    for (int pt = 0; pt < 4; ++pt) {
        float v = outp_[pt];
        v += __shfl_xor(v, 16, 64);
        v += __shfl_xor(v, 32, 64);
        vred[pt] = v;
    }
    if (l < 16) {
        #pragma unroll
        for (int pt = 0; pt < 4; ++pt)
            out[(size_t)b * N_PTS + p0 + pbase + pt * 16 + lrow] = vred[pt] + b3v;
    }
}

// ================= FALLBACK: fused single kernel (R6) =================
#define HB_OFF     0
#define BOUNCE_OFF 40960
#define W2H_OFF    96256
#define W2L_OFF    119552
#define W1H_OFF    142848
#define W1L_OFF    148224
#define B1_OFF     153600
#define B2_OFF     154048
#define W3_OFF     154496
#define LDS_TOTAL  154944

__global__ __launch_bounds__(512, 2) void fused_kernel(
    const float* __restrict__ x,
    const float* __restrict__ wvb,
    const float* __restrict__ mb0, const float* __restrict__ mb1,
    const float* __restrict__ mb2, const float* __restrict__ mb3,
    const float* __restrict__ w1, const float* __restrict__ b1,
    const float* __restrict__ w2, const float* __restrict__ b2,
    const float* __restrict__ w3, const float* __restrict__ b3,
    float* __restrict__ out) {
    extern __shared__ char smem[];
    float* lds_hb     = (float*)(smem + HB_OFF);
    float* lds_bounce = (float*)(smem + BOUNCE_OFF);
    short* lds_w2h    = (short*)(smem + W2H_OFF);
    short* lds_w2l    = (short*)(smem + W2L_OFF);
    short* lds_w1h    = (short*)(smem + W1H_OFF);
    short* lds_w1l    = (short*)(smem + W1L_OFF);
    float* lds_b1     = (float*)(smem + B1_OFF);
    float* lds_b2     = (float*)(smem + B2_OFF);
    float* lds_w3     = (float*)(smem + W3_OFF);

    const int b  = blockIdx.x >> 6;
    const int p0 = (blockIdx.x & 63) * 512;

    for (int idx = threadIdx.x; idx < 112 * 104; idx += 512) {
        int o = idx / 104, k = idx - o * 104;
        float v = (o < 100 && k < 100) ? w2[o * 100 + k] : 0.f;
        unsigned ua = __float_as_uint(v);
        float rv = v - __uint_as_float(ua & 0xffff0000u);
        lds_w2h[idx] = (short)(ua >> 16);
        lds_w2l[idx] = (short)(__float_as_uint(rv) >> 16);
    }
    for (int idx = threadIdx.x; idx < 112 * 24; idx += 512) {
        int o = idx / 24, k = idx - o * 24;
        float v = (o < 100 && k < 16) ? w1[o * 16 + k] : 0.f;
        unsigned ua = __float_as_uint(v);
        float rv = v - __uint_as_float(ua & 0xffff0000u);
        lds_w1h[idx] = (short)(ua >> 16);
        lds_w1l[idx] = (short)(__float_as_uint(rv) >> 16);
    }
    if (threadIdx.x < 112) {
        int o = threadIdx.x;
        lds_b1[o] = (o < 100) ? b1[o] : 0.f;
        lds_b2[o] = (o < 100) ? b2[o] : 0.f;
        lds_w3[o] = (o < 100) ? w3[o] : 0.f;
    }

    const int p = p0 + threadIdx.x;
#define DH(i) float h_##i;
    REP62(DH)
#undef DH
    {
        float x0 = x[2 * p], x1 = x[2 * p + 1];
        POSENC_BODY
    }
    const float* wv0 = wvb + b * 992;
    const float* wv1 = wvb + 15872 + b * 256;
    const float* wv2 = wvb + 15872 + 4096 + b * 256;
    const float* wv3 = wvb + 15872 + 8192 + b * 256;
#define DHA(i) float ha_##i;
    REP16(DHA)
#undef DHA
#define DHB(i) float hb_##i;
    REP16(DHB)
#undef DHB
    HYPER_BODY
    {
        f32x4* rowp = (f32x4*)(lds_hb + threadIdx.x * 20);
        f32x4 t0 = {hb_0,  hb_1,  hb_2,  hb_3};
        f32x4 t1 = {hb_4,  hb_5,  hb_6,  hb_7};
        f32x4 t2 = {hb_8,  hb_9,  hb_10, hb_11};
        f32x4 t3 = {hb_12, hb_13, hb_14, hb_15};
        rowp[0] = t0; rowp[1] = t1; rowp[2] = t2; rowp[3] = t3;
    }
    __syncthreads();

    const int l    = threadIdx.x & 63;
    const int w    = threadIdx.x >> 6;
    const int lrow = l & 15;
    const int lkg  = l >> 4;
    float* bounce = lds_bounce + w * (16 * 108);
    const int pbase = w * 64;
    const float b3v = b3[0];
    const f32x4 FZ = {0.f, 0.f, 0.f, 0.f};

    short8 hbh[4], hbl[4];
    #pragma unroll
    for (int pt = 0; pt < 4; ++pt) {
        const float* src = lds_hb + (pbase + pt * 16 + lrow) * 20 + (lkg & 1) * 8;
        f32x4 f0 = *(const f32x4*)src;
        f32x4 f1 = *(const f32x4*)(src + 4);
        if (lkg >= 2) { f0 = FZ; f1 = FZ; }
        packfrag(f0, f1, hbh[pt], hbl[pt]);
    }

    float outp_[4];
    #pragma unroll
    for (int pt = 0; pt < 4; ++pt) outp_[pt] = 0.f;

    short8 h2h[4][4], h2l[4][4];
    #pragma unroll
    for (int pt = 0; pt < 4; ++pt) {
        #pragma unroll
        for (int fmt = 0; fmt < 7; ++fmt) {
            f32x4 acc;
            #pragma unroll
            for (int r = 0; r < 4; ++r) acc[r] = lds_b1[fmt * 16 + lkg * 4 + r];
            short8 ah = *(const short8*)(lds_w1h + (fmt * 16 + lrow) * 24 + (lkg & 1) * 8);
            short8 al = *(const short8*)(lds_w1l + (fmt * 16 + lrow) * 24 + (lkg & 1) * 8);
            if (lkg >= 2) { ah = s8zero(); al = s8zero(); }
            acc = mfma16(ah, hbh[pt], acc);
            acc = mfma16(ah, hbl[pt], acc);
            acc = mfma16(al, hbh[pt], acc);
            f32x4 sv;
            #pragma unroll
            for (int r = 0; r < 4; ++r) sv[r] = silu_f(acc[r]);
            if (!(fmt == 6 && lkg == 3))
                *(f32x4*)(bounce + lrow * 108 + fmt * 16 + lkg * 4) = sv;
        }
        #pragma unroll
        for (int ks = 0; ks < 4; ++ks) {
            int kb = ks * 32 + lkg * 8;
            bool act = kb < 104;
            int kba = act ? kb : 0;
            const float* s2 = bounce + lrow * 108 + kba;
            f32x4 f0 = *(const f32x4*)s2;
            f32x4 f1 = *(const f32x4*)(s2 + 4);
            if (!act) { f0 = FZ; f1 = FZ; }
            packfrag(f0, f1, h2h[pt][ks], h2l[pt][ks]);
        }
    }

    #pragma unroll
    for (int fmt = 0; fmt < 7; ++fmt) {
        float bi[4], w3r[4];
        #pragma unroll
        for (int r = 0; r < 4; ++r) {
            bi[r]  = lds_b2[fmt * 16 + lkg * 4 + r];
            w3r[r] = lds_w3[fmt * 16 + lkg * 4 + r];
        }
        f32x4 acc[4];
        #pragma unroll
        for (int pt = 0; pt < 4; ++pt) { f32x4 t = {bi[0], bi[1], bi[2], bi[3]}; acc[pt] = t; }
        #pragma unroll
        for (int ks = 0; ks < 4; ++ks) {
            int kb = ks * 32 + lkg * 8;
            bool act = kb < 104;
            int kba = act ? kb : 0;
            short8 ah = *(const short8*)(lds_w2h + (fmt * 16 + lrow) * 104 + kba);
            short8 al = *(const short8*)(lds_w2l + (fmt * 16 + lrow) * 104 + kba);
            if (!act) { ah = s8zero(); al = s8zero(); }
            #pragma unroll
            for (int pt = 0; pt < 4; ++pt) {
                acc[pt] = mfma16(ah, h2h[pt][ks], acc[pt]);
                acc[pt] = mfma16(ah, h2l[pt][ks], acc[pt]);
                acc[pt] = mfma16(al, h2h[pt][ks], acc[pt]);
            }
        }
        #pragma unroll
        for (int pt = 0; pt < 4; ++pt) {
            #pragma unroll
            for (int r = 0; r < 4; ++r)
                outp_[pt] = fmaf(silu_f(acc[pt][r]), w3r[r], outp_[pt]);
        }
    }

    float vred[4];
    #pragma unroll
    for (int pt = 0; pt < 4; ++pt) {
        float v = outp_[pt];
        v += __shfl_xor(v, 16, 64);
        v += __shfl_xor(v, 32, 64);
        vred[pt] = v;
    }
    if (l < 16) {
        #pragma unroll
        for (int pt = 0; pt < 4; ++pt)
            out[(size_t)b * N_PTS + p0 + pbase + pt * 16 + lrow] = vred[pt] + b3v;
    }
}

// ---------------- launcher ----------------
extern "C" void kernel_launch(void* const* d_in, const int* in_sizes, int n_in,
                              void* d_out, int out_size, void* d_ws, size_t ws_size,
                              hipStream_t stream) {
    const float* x = (const float*)d_in[0];
    const float* latent = (const float*)d_in[1];
    const float *pw[4], *pb[4], *lnw[4], *lnb[4], *mb[4];
    for (int l = 0; l < 4; l++) {
        pw[l]  = (const float*)d_in[2 + 5 * l];
        pb[l]  = (const float*)d_in[3 + 5 * l];
        lnw[l] = (const float*)d_in[4 + 5 * l];
        lnb[l] = (const float*)d_in[5 + 5 * l];
        mb[l]  = (const float*)d_in[6 + 5 * l];
    }
    const float* w1 = (const float*)d_in[22];
    const float* b1 = (const float*)d_in[23];
    const float* w2 = (const float*)d_in[24];
    const float* b2 = (const float*)d_in[25];
    const float* w3 = (const float*)d_in[26];
    const float* b3 = (const float*)d_in[27];

    float* wsf = (float*)d_ws;
    const size_t WV_FLOATS = 15872 + 3 * 4096;              // 28160
    const size_t HB_FLOATS = (size_t)BATCH * 16 * N_PTS;    // 8,388,608 (32 MB)
    bool big = ws_size >= (WV_FLOATS + HB_FLOATS) * sizeof(float);

    float* wvb = wsf;
    float* hbg = wsf + WV_FLOATS;

    wv_kernel<<<1024, 64, 0, stream>>>(latent,
        pw[0], pb[0], lnw[0], lnb[0],
        pw[1], pb[1], lnw[1], lnb[1],
        pw[2], pb[2], lnw[2], lnb[2],
        pw[3], pb[3], lnw[3], lnb[3],
        wvb);

    if (big) {
        hyper_kernel<<<BATCH * (N_PTS / 256), 256, 0, stream>>>(
            x, wvb, mb[0], mb[1], mb[2], mb[3], hbg);
        hipFuncSetAttribute((const void*)mfma_kernel,
                            hipFuncAttributeMaxDynamicSharedMemorySize, MB_LDS_TOTAL);
        mfma_kernel<<<BATCH * (N_PTS / 512), 512, MB_LDS_TOTAL, stream>>>(
            hbg, w1, b1, w2, b2, w3, b3, (float*)d_out);
    } else {
        hipFuncSetAttribute((const void*)fused_kernel,
                            hipFuncAttributeMaxDynamicSharedMemorySize, LDS_TOTAL);
        fused_kernel<<<BATCH * (N_PTS / 512), 512, LDS_TOTAL, stream>>>(
            x, wvb, mb[0], mb[1], mb[2], mb[3],
            w1, b1, w2, b2, w3, b3, (float*)d_out);
    }
}

// Round 9
// 193.340 us; speedup vs baseline: 1.5252x; 1.5252x over previous
//
#include <hip/hip_runtime.h>

#define N_PTS 32768
#define BATCH 16
#define PIO2F 1.5707963705062866f

// ---------------- types / helpers ----------------
typedef __attribute__((ext_vector_type(8))) short short8;
typedef __attribute__((ext_vector_type(4))) float f32x4;

union S8u { short8 v; unsigned u[4]; };

__device__ __forceinline__ float silu_f(float v) {
    return v * __builtin_amdgcn_rcpf(1.0f + __expf(-v));
}

__device__ __forceinline__ float wave_sum(float v) {
    #pragma unroll
    for (int off = 1; off < 64; off <<= 1) v += __shfl_xor(v, off, 64);
    return v;
}

__device__ __forceinline__ void bfsplit2(float a, float b, unsigned& hi, unsigned& lo) {
    unsigned ua = __float_as_uint(a), ub = __float_as_uint(b);
    hi = (ua >> 16) | (ub & 0xffff0000u);
    float ra = a - __uint_as_float(ua & 0xffff0000u);
    float rb = b - __uint_as_float(ub & 0xffff0000u);
    lo = (__float_as_uint(ra) >> 16) | (__float_as_uint(rb) & 0xffff0000u);
}

__device__ __forceinline__ f32x4 mfma16(short8 a, short8 b, f32x4 c) {
    return __builtin_amdgcn_mfma_f32_16x16x32_bf16(a, b, c, 0, 0, 0);
}

__device__ __forceinline__ short8 s8zero() {
    S8u t; t.u[0] = 0; t.u[1] = 0; t.u[2] = 0; t.u[3] = 0; return t.v;
}

__device__ __forceinline__ void packfrag(f32x4 f0, f32x4 f1, short8& h, short8& l) {
    S8u th, tl;
    bfsplit2(f0[0], f0[1], th.u[0], tl.u[0]);
    bfsplit2(f0[2], f0[3], th.u[1], tl.u[1]);
    bfsplit2(f1[0], f1[1], th.u[2], tl.u[2]);
    bfsplit2(f1[2], f1[3], th.u[3], tl.u[3]);
    h = th.v; l = tl.v;
}

// split one f32 into hi/lo bf16 shorts
__device__ __forceinline__ void split1(float v, short& h, short& l) {
    unsigned ua = __float_as_uint(v);
    float rv = v - __uint_as_float(ua & 0xffff0000u);
    h = (short)(ua >> 16);
    l = (short)(__float_as_uint(rv) >> 16);
}

// ---------------- kernel 1: hyper-weights wv (latent einsum + LN) ----------------
__global__ void wv_kernel(
    const float* __restrict__ latent,
    const float* __restrict__ pw0, const float* __restrict__ pb0,
    const float* __restrict__ lnw0, const float* __restrict__ lnb0,
    const float* __restrict__ pw1, const float* __restrict__ pb1,
    const float* __restrict__ lnw1, const float* __restrict__ lnb1,
    const float* __restrict__ pw2, const float* __restrict__ pb2,
    const float* __restrict__ lnw2, const float* __restrict__ lnb2,
    const float* __restrict__ pw3, const float* __restrict__ pb3,
    const float* __restrict__ lnw3, const float* __restrict__ lnb3,
    float* __restrict__ wvb) {
    int blk = blockIdx.x;
    int l = blk >> 8;
    int rest = blk & 255;
    int b = rest >> 4, o = rest & 15;
    int c = threadIdx.x;

    const float *pw, *pb, *lnw, *lnb;
    float* outp;
    int ch;
    switch (l) {
        case 0:  pw = pw0; pb = pb0; lnw = lnw0; lnb = lnb0; outp = wvb;                 ch = 62; break;
        case 1:  pw = pw1; pb = pb1; lnw = lnw1; lnb = lnb1; outp = wvb + 15872;         ch = 16; break;
        case 2:  pw = pw2; pb = pb2; lnw = lnw2; lnb = lnb2; outp = wvb + 15872 + 4096;  ch = 16; break;
        default: pw = pw3; pb = pb3; lnw = lnw3; lnb = lnb3; outp = wvb + 15872 + 8192;  ch = 16; break;
    }
    const float* lat = latent + ((size_t)(b * 64 + l * 16 + o)) * 64;
    float dot = 0.f;
    if (c < ch) {
        const float* pr = pw + ((size_t)(o * ch + c)) * 64;
        #pragma unroll
        for (int d0 = 0; d0 < 64; d0++) dot += lat[d0] * pr[d0];
    }
    float act = (c < ch) ? dot : 0.f;
    float mu = wave_sum(act) * (1.0f / ch);
    float diff = (c < ch) ? (dot - mu) : 0.f;
    float var = wave_sum(diff * diff) * (1.0f / ch);
    float norm = diff * rsqrtf(var + 1e-5f);
    if (c < ch) outp[(size_t)(b * 16 + o) * ch + c] = norm * lnw[c] + lnb[c] + pb[o * ch + c];
}

// ---------------- LDS layout (bytes) ----------------
#define BOUNCE_OFF  0            // f32 8 x [16][108]  55296
#define W2H_OFF     55296        // short [112][104]   23296
#define W2L_OFF     78592        // short [112][104]   23296
#define W1H_OFF     101888       // short [112][24]     5376
#define W1L_OFF     107264       // short [112][24]     5376
#define B1_OFF      112640       // f32 [112]            448
#define B2_OFF      113088       // f32 [112]            448
#define W3_OFF      113536       // f32 [112]            448
#define WV0H_OFF    113984       // short [16][72]      2304
#define WV0L_OFF    116288       // short [16][72]      2304
#define WV123H_OFF  118592       // short [3][16][24]   2304
#define WV123L_OFF  120896       // short [3][16][24]   2304
#define MB_LDS_OFF  123200       // f32 [4][16]          256
#define LDS_TOTAL   123456

// ---------------- kernel 2: EVERYTHING per point on MFMA ----------------
// Block = 512 (8 waves), each wave owns 64 points (4 point-tiles of 16).
// Grid = 16 batches * 64. Per point-tile:
//   posenc computed per-lane DIRECTLY in B-fragment layout (16 sinf/lane),
//   layer0 (K=64) -> silu -> bounce -> layers 1..3 (K=16 each) -> hb frag,
//   w1 (7 fmt) -> bounce -> h2 frags; then w2 (K=104) + fused silu/w3 epilogue.
// 3-term bf16 hi/lo split throughout (~fp32 precision).
__global__ __launch_bounds__(512, 2) void mfma_kernel(
    const float* __restrict__ xg, const float* __restrict__ wvb,
    const float* __restrict__ mb0, const float* __restrict__ mb1,
    const float* __restrict__ mb2, const float* __restrict__ mb3,
    const float* __restrict__ w1, const float* __restrict__ b1,
    const float* __restrict__ w2, const float* __restrict__ b2,
    const float* __restrict__ w3, const float* __restrict__ b3,
    float* __restrict__ out) {
    extern __shared__ char smem[];
    float* lds_bounce = (float*)(smem + BOUNCE_OFF);
    short* lds_w2h    = (short*)(smem + W2H_OFF);
    short* lds_w2l    = (short*)(smem + W2L_OFF);
    short* lds_w1h    = (short*)(smem + W1H_OFF);
    short* lds_w1l    = (short*)(smem + W1L_OFF);
    float* lds_b1     = (float*)(smem + B1_OFF);
    float* lds_b2     = (float*)(smem + B2_OFF);
    float* lds_w3     = (float*)(smem + W3_OFF);
    short* lds_wv0h   = (short*)(smem + WV0H_OFF);
    short* lds_wv0l   = (short*)(smem + WV0L_OFF);
    short* lds_wvh    = (short*)(smem + WV123H_OFF);
    short* lds_wvl    = (short*)(smem + WV123L_OFF);
    float* lds_mb     = (float*)(smem + MB_LDS_OFF);

    const int b  = blockIdx.x >> 6;
    const int p0 = (blockIdx.x & 63) * 512;

    // ---- stage shared weights (hi/lo split) ----
    for (int idx = threadIdx.x; idx < 112 * 104; idx += 512) {
        int o = idx / 104, k = idx - o * 104;
        float v = (o < 100 && k < 100) ? w2[o * 100 + k] : 0.f;
        split1(v, lds_w2h[idx], lds_w2l[idx]);
    }
    for (int idx = threadIdx.x; idx < 112 * 24; idx += 512) {
        int o = idx / 24, k = idx - o * 24;
        float v = (o < 100 && k < 16) ? w1[o * 16 + k] : 0.f;
        split1(v, lds_w1h[idx], lds_w1l[idx]);
    }
    // ---- stage batch-specific hyper weights ----
    const float* wv0g = wvb + b * 992;                 // [16][62]
    for (int idx = threadIdx.x; idx < 16 * 72; idx += 512) {
        int o = idx / 72, k = idx - o * 72;
        float v = (k < 62) ? wv0g[o * 62 + k] : 0.f;
        split1(v, lds_wv0h[idx], lds_wv0l[idx]);
    }
    const float* wv1g = wvb + 15872 + b * 256;         // [16][16] each
    const float* wv2g = wvb + 15872 + 4096 + b * 256;
    const float* wv3g = wvb + 15872 + 8192 + b * 256;
    for (int idx = threadIdx.x; idx < 3 * 16 * 24; idx += 512) {
        int li = idx / 384, rest = idx - li * 384;
        int o = rest / 24, k = rest - o * 24;
        const float* src = (li == 0) ? wv1g : (li == 1) ? wv2g : wv3g;
        float v = (k < 16) ? src[o * 16 + k] : 0.f;
        split1(v, lds_wvh[idx], lds_wvl[idx]);
    }
    if (threadIdx.x < 112) {
        int o = threadIdx.x;
        lds_b1[o] = (o < 100) ? b1[o] : 0.f;
        lds_b2[o] = (o < 100) ? b2[o] : 0.f;
        lds_w3[o] = (o < 100) ? w3[o] : 0.f;
    }
    if (threadIdx.x >= 128 && threadIdx.x < 192) {
        int t = threadIdx.x - 128;
        int li = t >> 4, o = t & 15;
        const float* mbp = (li == 0) ? mb0 : (li == 1) ? mb1 : (li == 2) ? mb2 : mb3;
        lds_mb[t] = mbp[o];
    }
    __syncthreads();

    const int l    = threadIdx.x & 63;
    const int w    = threadIdx.x >> 6;
    const int lrow = l & 15;   // point-col (B) / out-row (A,C)
    const int lkg  = l >> 4;   // k-group
    float* bounce = lds_bounce + w * (16 * 108);
    const int pbase = w * 64;
    const float b3v = b3[0];
    const f32x4 FZ = {0.f, 0.f, 0.f, 0.f};

    float outp_[4];
    #pragma unroll
    for (int pt = 0; pt < 4; ++pt) outp_[pt] = 0.f;

    short8 h2h[4][4], h2l[4][4];

    #pragma unroll 1
    for (int pt = 0; pt < 4; ++pt) {
        const int pcol = p0 + pbase + pt * 16 + lrow;
        const float x0 = xg[2 * pcol], x1 = xg[2 * pcol + 1];

        // ---- posenc directly in B-frag layout ----
        // frag0: features f = 8*lkg + j (f in 0..31); frag1: f = 32 + 8*lkg + j
        float pf[8];
        short8 pb0h, pb0l, pb1h, pb1l;
        #pragma unroll
        for (int j = 0; j < 8; ++j) {
            int idx2 = 8 * lkg + j - 2;               // sin-feature index
            int s = idx2 >> 1;
            float sc = __uint_as_float((unsigned)(127 + s) << 23);
            float xa = (idx2 & 1) ? x1 : x0;
            float v = sinf(xa * sc);
            if (lkg == 0 && j == 0) v = x0;
            if (lkg == 0 && j == 1) v = x1;
            pf[j] = v;
        }
        {
            f32x4 f0 = {pf[0], pf[1], pf[2], pf[3]};
            f32x4 f1 = {pf[4], pf[5], pf[6], pf[7]};
            packfrag(f0, f1, pb0h, pb0l);
        }
        #pragma unroll
        for (int j = 0; j < 8; ++j) {
            int t = 8 * lkg + j;                      // cos-branch index
            int s = t >> 1;
            float sc = __uint_as_float((unsigned)(127 + s) << 23);
            float xa = (t & 1) ? x1 : x0;
            float v = sinf(fmaf(xa, sc, PIO2F));
            if (t >= 30) v = 0.f;                     // features 62,63 pad
            pf[j] = v;
        }
        {
            f32x4 f0 = {pf[0], pf[1], pf[2], pf[3]};
            f32x4 f1 = {pf[4], pf[5], pf[6], pf[7]};
            packfrag(f0, f1, pb1h, pb1l);
        }

        // ---- layer 0: K=64 (2 k-steps x 3 terms) ----
        f32x4 acc;
        #pragma unroll
        for (int r = 0; r < 4; ++r) acc[r] = lds_mb[0 * 16 + lkg * 4 + r];
        {
            short8 ah = *(const short8*)(lds_wv0h + lrow * 72 + lkg * 8);
            short8 al = *(const short8*)(lds_wv0l + lrow * 72 + lkg * 8);
            acc = mfma16(ah, pb0h, acc);
            acc = mfma16(ah, pb0l, acc);
            acc = mfma16(al, pb0h, acc);
            ah = *(const short8*)(lds_wv0h + lrow * 72 + 32 + lkg * 8);
            al = *(const short8*)(lds_wv0l + lrow * 72 + 32 + lkg * 8);
            acc = mfma16(ah, pb1h, acc);
            acc = mfma16(ah, pb1l, acc);
            acc = mfma16(al, pb1h, acc);
        }

        // ---- layers 1..3: K=16, MFMA->silu->bounce->refrag ----
        short8 fh, fl;
        #pragma unroll
        for (int li = 0; li < 3; ++li) {
            // silu + bounce previous acc (16 feats)
            f32x4 sv;
            #pragma unroll
            for (int r = 0; r < 4; ++r) sv[r] = silu_f(acc[r]);
            *(f32x4*)(bounce + lrow * 108 + lkg * 4) = sv;
            // refrag from bounce
            {
                const float* s2 = bounce + lrow * 108 + 8 * (lkg & 1);
                f32x4 f0 = *(const f32x4*)s2;
                f32x4 f1 = *(const f32x4*)(s2 + 4);
                if (lkg >= 2) { f0 = FZ; f1 = FZ; }
                packfrag(f0, f1, fh, fl);
            }
            #pragma unroll
            for (int r = 0; r < 4; ++r) acc[r] = lds_mb[(li + 1) * 16 + lkg * 4 + r];
            short8 ah = *(const short8*)(lds_wvh + (li * 16 + lrow) * 24 + (lkg & 1) * 8);
            short8 al = *(const short8*)(lds_wvl + (li * 16 + lrow) * 24 + (lkg & 1) * 8);
            if (lkg >= 2) { ah = s8zero(); al = s8zero(); }
            acc = mfma16(ah, fh, acc);
            acc = mfma16(ah, fl, acc);
            acc = mfma16(al, fh, acc);
        }
        // hb = silu(layer3) -> bounce -> hb frag
        {
            f32x4 sv;
            #pragma unroll
            for (int r = 0; r < 4; ++r) sv[r] = silu_f(acc[r]);
            *(f32x4*)(bounce + lrow * 108 + lkg * 4) = sv;
        }
        short8 hbh, hbl;
        {
            const float* s2 = bounce + lrow * 108 + 8 * (lkg & 1);
            f32x4 f0 = *(const f32x4*)s2;
            f32x4 f1 = *(const f32x4*)(s2 + 4);
            if (lkg >= 2) { f0 = FZ; f1 = FZ; }
            packfrag(f0, f1, hbh, hbl);
        }

        // ---- w1: hb(16) -> h2(100), 7 fmt ----
        #pragma unroll
        for (int fmt = 0; fmt < 7; ++fmt) {
            f32x4 a1;
            #pragma unroll
            for (int r = 0; r < 4; ++r) a1[r] = lds_b1[fmt * 16 + lkg * 4 + r];
            short8 ah = *(const short8*)(lds_w1h + (fmt * 16 + lrow) * 24 + (lkg & 1) * 8);
            short8 al = *(const short8*)(lds_w1l + (fmt * 16 + lrow) * 24 + (lkg & 1) * 8);
            if (lkg >= 2) { ah = s8zero(); al = s8zero(); }
            a1 = mfma16(ah, hbh, a1);
            a1 = mfma16(ah, hbl, a1);
            a1 = mfma16(al, hbh, a1);
            f32x4 sv;
            #pragma unroll
            for (int r = 0; r < 4; ++r) sv[r] = silu_f(a1[r]);
            if (!(fmt == 6 && lkg == 3))
                *(f32x4*)(bounce + lrow * 108 + fmt * 16 + lkg * 4) = sv;
        }
        // h2 frags (K=104 padded to 128)
        #pragma unroll
        for (int ks = 0; ks < 4; ++ks) {
            int kb = ks * 32 + lkg * 8;
            bool act = kb < 104;
            int kba = act ? kb : 0;
            const float* s2 = bounce + lrow * 108 + kba;
            f32x4 f0 = *(const f32x4*)s2;
            f32x4 f1 = *(const f32x4*)(s2 + 4);
            if (!act) { f0 = FZ; f1 = FZ; }
            packfrag(f0, f1, h2h[pt][ks], h2l[pt][ks]);
        }
    }

    // ---- w2: weights from LDS, h2 resident; fused silu/w3 epilogue ----
    #pragma unroll
    for (int fmt = 0; fmt < 7; ++fmt) {
        float bi[4], w3r[4];
        #pragma unroll
        for (int r = 0; r < 4; ++r) {
            bi[r]  = lds_b2[fmt * 16 + lkg * 4 + r];
            w3r[r] = lds_w3[fmt * 16 + lkg * 4 + r];
        }
        f32x4 acc[4];
        #pragma unroll
        for (int pt = 0; pt < 4; ++pt) { f32x4 t = {bi[0], bi[1], bi[2], bi[3]}; acc[pt] = t; }
        #pragma unroll
        for (int ks = 0; ks < 4; ++ks) {
            int kb = ks * 32 + lkg * 8;
            bool act = kb < 104;
            int kba = act ? kb : 0;
            short8 ah = *(const short8*)(lds_w2h + (fmt * 16 + lrow) * 104 + kba);
            short8 al = *(const short8*)(lds_w2l + (fmt * 16 + lrow) * 104 + kba);
            if (!act) { ah = s8zero(); al = s8zero(); }
            #pragma unroll
            for (int pt = 0; pt < 4; ++pt) {
                acc[pt] = mfma16(ah, h2h[pt][ks], acc[pt]);
                acc[pt] = mfma16(ah, h2l[pt][ks], acc[pt]);
                acc[pt] = mfma16(al, h2h[pt][ks], acc[pt]);
            }
        }
        #pragma unroll
        for (int pt = 0; pt < 4; ++pt) {
            #pragma unroll
            for (int r = 0; r < 4; ++r)
                outp_[pt] = fmaf(silu_f(acc[pt][r]), w3r[r], outp_[pt]);
        }
    }

    // reduce across the 4 lane-groups and store
    float vred[4];
    #pragma unroll
    for (int pt = 0; pt < 4; ++pt) {
        float v = outp_[pt];
        v += __shfl_xor(v, 16, 64);
        v += __shfl_xor(v, 32, 64);
        vred[pt] = v;
    }
    if (l < 16) {
        #pragma unroll
        for (int pt = 0; pt < 4; ++pt)
            out[(size_t)b * N_PTS + p0 + pbase + pt * 16 + lrow] = vred[pt] + b3v;
    }
}

// ---------------- launcher ----------------
extern "C" void kernel_launch(void* const* d_in, const int* in_sizes, int n_in,
                              void* d_out, int out_size, void* d_ws, size_t ws_size,
                              hipStream_t stream) {
    const float* x = (const float*)d_in[0];
    const float* latent = (const float*)d_in[1];
    const float *pw[4], *pb[4], *lnw[4], *lnb[4], *mb[4];
    for (int l = 0; l < 4; l++) {
        pw[l]  = (const float*)d_in[2 + 5 * l];
        pb[l]  = (const float*)d_in[3 + 5 * l];
        lnw[l] = (const float*)d_in[4 + 5 * l];
        lnb[l] = (const float*)d_in[5 + 5 * l];
        mb[l]  = (const float*)d_in[6 + 5 * l];
    }
    const float* w1 = (const float*)d_in[22];
    const float* b1 = (const float*)d_in[23];
    const float* w2 = (const float*)d_in[24];
    const float* b2 = (const float*)d_in[25];
    const float* w3 = (const float*)d_in[26];
    const float* b3 = (const float*)d_in[27];

    float* wvb = (float*)d_ws;   // 28160 floats

    wv_kernel<<<1024, 64, 0, stream>>>(latent,
        pw[0], pb[0], lnw[0], lnb[0],
        pw[1], pb[1], lnw[1], lnb[1],
        pw[2], pb[2], lnw[2], lnb[2],
        pw[3], pb[3], lnw[3], lnb[3],
        wvb);

    hipFuncSetAttribute((const void*)mfma_kernel,
                        hipFuncAttributeMaxDynamicSharedMemorySize, LDS_TOTAL);
    mfma_kernel<<<BATCH * (N_PTS / 512), 512, LDS_TOTAL, stream>>>(
        x, wvb, mb[0], mb[1], mb[2], mb[3],
        w1, b1, w2, b2, w3, b3, (float*)d_out);
}

// Round 10
// 149.872 us; speedup vs baseline: 1.9675x; 1.2900x over previous
//
#include <hip/hip_runtime.h>

#define N_PTS 32768
#define BATCH 16
#define PIO2F 1.5707963705062866f

// ---------------- types / helpers ----------------
typedef __attribute__((ext_vector_type(8))) short short8;
typedef __attribute__((ext_vector_type(4))) float f32x4;

union S8u { short8 v; unsigned u[4]; };

__device__ __forceinline__ float silu_f(float v) {
    return v * __builtin_amdgcn_rcpf(1.0f + __expf(-v));
}

__device__ __forceinline__ float wave_sum(float v) {
    #pragma unroll
    for (int off = 1; off < 64; off <<= 1) v += __shfl_xor(v, off, 64);
    return v;
}

__device__ __forceinline__ void bfsplit2(float a, float b, unsigned& hi, unsigned& lo) {
    unsigned ua = __float_as_uint(a), ub = __float_as_uint(b);
    hi = (ua >> 16) | (ub & 0xffff0000u);
    float ra = a - __uint_as_float(ua & 0xffff0000u);
    float rb = b - __uint_as_float(ub & 0xffff0000u);
    lo = (__float_as_uint(ra) >> 16) | (__float_as_uint(rb) & 0xffff0000u);
}

__device__ __forceinline__ f32x4 mfma16(short8 a, short8 b, f32x4 c) {
    return __builtin_amdgcn_mfma_f32_16x16x32_bf16(a, b, c, 0, 0, 0);
}

__device__ __forceinline__ short8 s8zero() {
    S8u t; t.u[0] = 0; t.u[1] = 0; t.u[2] = 0; t.u[3] = 0; return t.v;
}

__device__ __forceinline__ void packfrag(f32x4 f0, f32x4 f1, short8& h, short8& l) {
    S8u th, tl;
    bfsplit2(f0[0], f0[1], th.u[0], tl.u[0]);
    bfsplit2(f0[2], f0[3], th.u[1], tl.u[1]);
    bfsplit2(f1[0], f1[1], th.u[2], tl.u[2]);
    bfsplit2(f1[2], f1[3], th.u[3], tl.u[3]);
    h = th.v; l = tl.v;
}

__device__ __forceinline__ void split1(float v, short& h, short& l) {
    unsigned ua = __float_as_uint(v);
    float rv = v - __uint_as_float(ua & 0xffff0000u);
    h = (short)(ua >> 16);
    l = (short)(__float_as_uint(rv) >> 16);
}

// ---------------- kernel 1: hyper-weights wv (latent einsum + LN) ----------------
__global__ void wv_kernel(
    const float* __restrict__ latent,
    const float* __restrict__ pw0, const float* __restrict__ pb0,
    const float* __restrict__ lnw0, const float* __restrict__ lnb0,
    const float* __restrict__ pw1, const float* __restrict__ pb1,
    const float* __restrict__ lnw1, const float* __restrict__ lnb1,
    const float* __restrict__ pw2, const float* __restrict__ pb2,
    const float* __restrict__ lnw2, const float* __restrict__ lnb2,
    const float* __restrict__ pw3, const float* __restrict__ pb3,
    const float* __restrict__ lnw3, const float* __restrict__ lnb3,
    float* __restrict__ wvb) {
    int blk = blockIdx.x;
    int l = blk >> 8;
    int rest = blk & 255;
    int b = rest >> 4, o = rest & 15;
    int c = threadIdx.x;

    const float *pw, *pb, *lnw, *lnb;
    float* outp;
    int ch;
    switch (l) {
        case 0:  pw = pw0; pb = pb0; lnw = lnw0; lnb = lnb0; outp = wvb;                 ch = 62; break;
        case 1:  pw = pw1; pb = pb1; lnw = lnw1; lnb = lnb1; outp = wvb + 15872;         ch = 16; break;
        case 2:  pw = pw2; pb = pb2; lnw = lnw2; lnb = lnb2; outp = wvb + 15872 + 4096;  ch = 16; break;
        default: pw = pw3; pb = pb3; lnw = lnw3; lnb = lnb3; outp = wvb + 15872 + 8192;  ch = 16; break;
    }
    const float* lat = latent + ((size_t)(b * 64 + l * 16 + o)) * 64;
    float dot = 0.f;
    if (c < ch) {
        const float* pr = pw + ((size_t)(o * ch + c)) * 64;
        #pragma unroll
        for (int d0 = 0; d0 < 64; d0++) dot += lat[d0] * pr[d0];
    }
    float act = (c < ch) ? dot : 0.f;
    float mu = wave_sum(act) * (1.0f / ch);
    float diff = (c < ch) ? (dot - mu) : 0.f;
    float var = wave_sum(diff * diff) * (1.0f / ch);
    float norm = diff * rsqrtf(var + 1e-5f);
    if (c < ch) outp[(size_t)(b * 16 + o) * ch + c] = norm * lnw[c] + lnb[c] + pb[o * ch + c];
}

// ---------------- LDS layout (bytes) ----------------
#define BOUNCE_OFF  0            // f32 8 x [16][108]  55296
#define W2H_OFF     55296        // short [112][104]   23296
#define W2L_OFF     78592        // short [112][104]   23296
#define W1H_OFF     101888       // short [112][24]     5376
#define W1L_OFF     107264       // short [112][24]     5376
#define B1_OFF      112640       // f32 [112]            448
#define B2_OFF      113088       // f32 [112]            448
#define W3_OFF      113536       // f32 [112]            448
#define WV0H_OFF    113984       // short [16][72]      2304
#define WV0L_OFF    116288       // short [16][72]      2304
#define WV123H_OFF  118592       // short [3][16][24]   2304
#define WV123L_OFF  120896       // short [3][16][24]   2304
#define MB_LDS_OFF  123200       // f32 [4][16]          256
#define LDS_TOTAL   123456

// ---------------- kernel 2: EVERYTHING per point on MFMA ----------------
// Block = 512 (8 waves), each wave owns 64 points (4 point-tiles of 16),
// and processes each point-tile END-TO-END (posenc..w3) so no fragment
// state crosses the pt-loop boundary: all arrays statically indexed, peak
// live set ~110 VGPRs -> structurally spill-proof (R9's h2h[pt][ks] with
// runtime pt went to scratch: 264 MB of spill traffic).
__global__ __launch_bounds__(512, 2) void mfma_kernel(
    const float* __restrict__ xg, const float* __restrict__ wvb,
    const float* __restrict__ mb0, const float* __restrict__ mb1,
    const float* __restrict__ mb2, const float* __restrict__ mb3,
    const float* __restrict__ w1, const float* __restrict__ b1,
    const float* __restrict__ w2, const float* __restrict__ b2,
    const float* __restrict__ w3, const float* __restrict__ b3,
    float* __restrict__ out) {
    extern __shared__ char smem[];
    float* lds_bounce = (float*)(smem + BOUNCE_OFF);
    short* lds_w2h    = (short*)(smem + W2H_OFF);
    short* lds_w2l    = (short*)(smem + W2L_OFF);
    short* lds_w1h    = (short*)(smem + W1H_OFF);
    short* lds_w1l    = (short*)(smem + W1L_OFF);
    float* lds_b1     = (float*)(smem + B1_OFF);
    float* lds_b2     = (float*)(smem + B2_OFF);
    float* lds_w3     = (float*)(smem + W3_OFF);
    short* lds_wv0h   = (short*)(smem + WV0H_OFF);
    short* lds_wv0l   = (short*)(smem + WV0L_OFF);
    short* lds_wvh    = (short*)(smem + WV123H_OFF);
    short* lds_wvl    = (short*)(smem + WV123L_OFF);
    float* lds_mb     = (float*)(smem + MB_LDS_OFF);

    const int b  = blockIdx.x >> 6;
    const int p0 = (blockIdx.x & 63) * 512;

    // ---- stage shared weights (hi/lo split) ----
    for (int idx = threadIdx.x; idx < 112 * 104; idx += 512) {
        int o = idx / 104, k = idx - o * 104;
        float v = (o < 100 && k < 100) ? w2[o * 100 + k] : 0.f;
        split1(v, lds_w2h[idx], lds_w2l[idx]);
    }
    for (int idx = threadIdx.x; idx < 112 * 24; idx += 512) {
        int o = idx / 24, k = idx - o * 24;
        float v = (o < 100 && k < 16) ? w1[o * 16 + k] : 0.f;
        split1(v, lds_w1h[idx], lds_w1l[idx]);
    }
    // ---- stage batch-specific hyper weights ----
    const float* wv0g = wvb + b * 992;                 // [16][62]
    for (int idx = threadIdx.x; idx < 16 * 72; idx += 512) {
        int o = idx / 72, k = idx - o * 72;
        float v = (k < 62) ? wv0g[o * 62 + k] : 0.f;
        split1(v, lds_wv0h[idx], lds_wv0l[idx]);
    }
    const float* wv1g = wvb + 15872 + b * 256;         // [16][16] each
    const float* wv2g = wvb + 15872 + 4096 + b * 256;
    const float* wv3g = wvb + 15872 + 8192 + b * 256;
    for (int idx = threadIdx.x; idx < 3 * 16 * 24; idx += 512) {
        int li = idx / 384, rest = idx - li * 384;
        int o = rest / 24, k = rest - o * 24;
        const float* src = (li == 0) ? wv1g : (li == 1) ? wv2g : wv3g;
        float v = (k < 16) ? src[o * 16 + k] : 0.f;
        split1(v, lds_wvh[idx], lds_wvl[idx]);
    }
    if (threadIdx.x < 112) {
        int o = threadIdx.x;
        lds_b1[o] = (o < 100) ? b1[o] : 0.f;
        lds_b2[o] = (o < 100) ? b2[o] : 0.f;
        lds_w3[o] = (o < 100) ? w3[o] : 0.f;
    }
    if (threadIdx.x >= 128 && threadIdx.x < 192) {
        int t = threadIdx.x - 128;
        int li = t >> 4, o = t & 15;
        const float* mbp = (li == 0) ? mb0 : (li == 1) ? mb1 : (li == 2) ? mb2 : mb3;
        lds_mb[t] = mbp[o];
    }
    __syncthreads();

    const int l    = threadIdx.x & 63;
    const int w    = threadIdx.x >> 6;
    const int lrow = l & 15;   // point-col (B) / out-row (A,C)
    const int lkg  = l >> 4;   // k-group
    float* bounce = lds_bounce + w * (16 * 108);
    const int pbase = w * 64;
    const float b3v = b3[0];
    const f32x4 FZ = {0.f, 0.f, 0.f, 0.f};

    #pragma unroll 1
    for (int pt = 0; pt < 4; ++pt) {
        const int pcol = p0 + pbase + pt * 16 + lrow;
        const float x0 = xg[2 * pcol], x1 = xg[2 * pcol + 1];

        // ---- posenc directly in B-frag layout ----
        float pf[8];
        short8 pb0h, pb0l, pb1h, pb1l;
        #pragma unroll
        for (int j = 0; j < 8; ++j) {
            int idx2 = 8 * lkg + j - 2;               // sin-feature index
            int s = idx2 >> 1;
            float sc = __uint_as_float((unsigned)(127 + s) << 23);
            float xa = (idx2 & 1) ? x1 : x0;
            float v = sinf(xa * sc);
            if (lkg == 0 && j == 0) v = x0;
            if (lkg == 0 && j == 1) v = x1;
            pf[j] = v;
        }
        {
            f32x4 f0 = {pf[0], pf[1], pf[2], pf[3]};
            f32x4 f1 = {pf[4], pf[5], pf[6], pf[7]};
            packfrag(f0, f1, pb0h, pb0l);
        }
        #pragma unroll
        for (int j = 0; j < 8; ++j) {
            int t = 8 * lkg + j;                      // cos-branch index
            int s = t >> 1;
            float sc = __uint_as_float((unsigned)(127 + s) << 23);
            float xa = (t & 1) ? x1 : x0;
            float v = sinf(fmaf(xa, sc, PIO2F));
            if (t >= 30) v = 0.f;                     // features 62,63 pad
            pf[j] = v;
        }
        {
            f32x4 f0 = {pf[0], pf[1], pf[2], pf[3]};
            f32x4 f1 = {pf[4], pf[5], pf[6], pf[7]};
            packfrag(f0, f1, pb1h, pb1l);
        }

        // ---- layer 0: K=64 (2 k-steps x 3 terms) ----
        f32x4 acc;
        #pragma unroll
        for (int r = 0; r < 4; ++r) acc[r] = lds_mb[0 * 16 + lkg * 4 + r];
        {
            short8 ah = *(const short8*)(lds_wv0h + lrow * 72 + lkg * 8);
            short8 al = *(const short8*)(lds_wv0l + lrow * 72 + lkg * 8);
            acc = mfma16(ah, pb0h, acc);
            acc = mfma16(ah, pb0l, acc);
            acc = mfma16(al, pb0h, acc);
            ah = *(const short8*)(lds_wv0h + lrow * 72 + 32 + lkg * 8);
            al = *(const short8*)(lds_wv0l + lrow * 72 + 32 + lkg * 8);
            acc = mfma16(ah, pb1h, acc);
            acc = mfma16(ah, pb1l, acc);
            acc = mfma16(al, pb1h, acc);
        }

        // ---- layers 1..3: K=16, MFMA->silu->bounce->refrag ----
        short8 fh, fl;
        #pragma unroll
        for (int li = 0; li < 3; ++li) {
            f32x4 sv;
            #pragma unroll
            for (int r = 0; r < 4; ++r) sv[r] = silu_f(acc[r]);
            *(f32x4*)(bounce + lrow * 108 + lkg * 4) = sv;
            {
                const float* s2 = bounce + lrow * 108 + 8 * (lkg & 1);
                f32x4 f0 = *(const f32x4*)s2;
                f32x4 f1 = *(const f32x4*)(s2 + 4);
                if (lkg >= 2) { f0 = FZ; f1 = FZ; }
                packfrag(f0, f1, fh, fl);
            }
            #pragma unroll
            for (int r = 0; r < 4; ++r) acc[r] = lds_mb[(li + 1) * 16 + lkg * 4 + r];
            short8 ah = *(const short8*)(lds_wvh + (li * 16 + lrow) * 24 + (lkg & 1) * 8);
            short8 al = *(const short8*)(lds_wvl + (li * 16 + lrow) * 24 + (lkg & 1) * 8);
            if (lkg >= 2) { ah = s8zero(); al = s8zero(); }
            acc = mfma16(ah, fh, acc);
            acc = mfma16(ah, fl, acc);
            acc = mfma16(al, fh, acc);
        }
        // hb = silu(layer3) -> bounce -> hb frag
        {
            f32x4 sv;
            #pragma unroll
            for (int r = 0; r < 4; ++r) sv[r] = silu_f(acc[r]);
            *(f32x4*)(bounce + lrow * 108 + lkg * 4) = sv;
        }
        short8 hbh, hbl;
        {
            const float* s2 = bounce + lrow * 108 + 8 * (lkg & 1);
            f32x4 f0 = *(const f32x4*)s2;
            f32x4 f1 = *(const f32x4*)(s2 + 4);
            if (lkg >= 2) { f0 = FZ; f1 = FZ; }
            packfrag(f0, f1, hbh, hbl);
        }

        // ---- w1: hb(16) -> h2(100), 7 fmt ----
        #pragma unroll
        for (int fmt = 0; fmt < 7; ++fmt) {
            f32x4 a1;
            #pragma unroll
            for (int r = 0; r < 4; ++r) a1[r] = lds_b1[fmt * 16 + lkg * 4 + r];
            short8 ah = *(const short8*)(lds_w1h + (fmt * 16 + lrow) * 24 + (lkg & 1) * 8);
            short8 al = *(const short8*)(lds_w1l + (fmt * 16 + lrow) * 24 + (lkg & 1) * 8);
            if (lkg >= 2) { ah = s8zero(); al = s8zero(); }
            a1 = mfma16(ah, hbh, a1);
            a1 = mfma16(ah, hbl, a1);
            a1 = mfma16(al, hbh, a1);
            f32x4 sv;
            #pragma unroll
            for (int r = 0; r < 4; ++r) sv[r] = silu_f(a1[r]);
            if (!(fmt == 6 && lkg == 3))
                *(f32x4*)(bounce + lrow * 108 + fmt * 16 + lkg * 4) = sv;
        }
        // h2 frags (K=104 padded to 128) — per-pt locals, static ks index
        short8 h2h[4], h2l[4];
        #pragma unroll
        for (int ks = 0; ks < 4; ++ks) {
            int kb = ks * 32 + lkg * 8;
            bool act = kb < 104;
            int kba = act ? kb : 0;
            const float* s2 = bounce + lrow * 108 + kba;
            f32x4 f0 = *(const f32x4*)s2;
            f32x4 f1 = *(const f32x4*)(s2 + 4);
            if (!act) { f0 = FZ; f1 = FZ; }
            packfrag(f0, f1, h2h[ks], h2l[ks]);
        }

        // ---- w2 for THIS point-tile: weights from LDS, fused silu/w3 epilogue ----
        float outv = 0.f;
        #pragma unroll
        for (int fmt = 0; fmt < 7; ++fmt) {
            f32x4 a2;
            #pragma unroll
            for (int r = 0; r < 4; ++r) a2[r] = lds_b2[fmt * 16 + lkg * 4 + r];
            #pragma unroll
            for (int ks = 0; ks < 4; ++ks) {
                int kb = ks * 32 + lkg * 8;
                bool act = kb < 104;
                int kba = act ? kb : 0;
                short8 ah = *(const short8*)(lds_w2h + (fmt * 16 + lrow) * 104 + kba);
                short8 al = *(const short8*)(lds_w2l + (fmt * 16 + lrow) * 104 + kba);
                if (!act) { ah = s8zero(); al = s8zero(); }
                a2 = mfma16(ah, h2h[ks], a2);
                a2 = mfma16(ah, h2l[ks], a2);
                a2 = mfma16(al, h2h[ks], a2);
            }
            #pragma unroll
            for (int r = 0; r < 4; ++r)
                outv = fmaf(silu_f(a2[r]), lds_w3[fmt * 16 + lkg * 4 + r], outv);
        }

        // reduce across the 4 lane-groups and store
        outv += __shfl_xor(outv, 16, 64);
        outv += __shfl_xor(outv, 32, 64);
        if (l < 16)
            out[(size_t)b * N_PTS + pcol] = outv + b3v;
    }
}

// ---------------- launcher ----------------
extern "C" void kernel_launch(void* const* d_in, const int* in_sizes, int n_in,
                              void* d_out, int out_size, void* d_ws, size_t ws_size,
                              hipStream_t stream) {
    const float* x = (const float*)d_in[0];
    const float* latent = (const float*)d_in[1];
    const float *pw[4], *pb[4], *lnw[4], *lnb[4], *mb[4];
    for (int l = 0; l < 4; l++) {
        pw[l]  = (const float*)d_in[2 + 5 * l];
        pb[l]  = (const float*)d_in[3 + 5 * l];
        lnw[l] = (const float*)d_in[4 + 5 * l];
        lnb[l] = (const float*)d_in[5 + 5 * l];
        mb[l]  = (const float*)d_in[6 + 5 * l];
    }
    const float* w1 = (const float*)d_in[22];
    const float* b1 = (const float*)d_in[23];
    const float* w2 = (const float*)d_in[24];
    const float* b2 = (const float*)d_in[25];
    const float* w3 = (const float*)d_in[26];
    const float* b3 = (const float*)d_in[27];

    float* wvb = (float*)d_ws;   // 28160 floats

    wv_kernel<<<1024, 64, 0, stream>>>(latent,
        pw[0], pb[0], lnw[0], lnb[0],
        pw[1], pb[1], lnw[1], lnb[1],
        pw[2], pb[2], lnw[2], lnb[2],
        pw[3], pb[3], lnw[3], lnb[3],
        wvb);

    hipFuncSetAttribute((const void*)mfma_kernel,
                        hipFuncAttributeMaxDynamicSharedMemorySize, LDS_TOTAL);
    mfma_kernel<<<BATCH * (N_PTS / 512), 512, LDS_TOTAL, stream>>>(
        x, wvb, mb[0], mb[1], mb[2], mb[3],
        w1, b1, w2, b2, w3, b3, (float*)d_out);
}

// Round 12
// 111.330 us; speedup vs baseline: 2.6487x; 1.3462x over previous
//
#include <hip/hip_runtime.h>

#define N_PTS 32768
#define BATCH 16
#define PIO2F 1.5707963705062866f

// ---------------- types / helpers ----------------
typedef __attribute__((ext_vector_type(8))) short short8;
typedef __attribute__((ext_vector_type(4))) float f32x4;

union S8u { short8 v; unsigned u[4]; };

__device__ __forceinline__ float silu_f(float v) {
    return v * __builtin_amdgcn_rcpf(1.0f + __expf(-v));
}

__device__ __forceinline__ float wave_sum(float v) {
    #pragma unroll
    for (int off = 1; off < 64; off <<= 1) v += __shfl_xor(v, off, 64);
    return v;
}

// Free compile-time fence making intra-wave cross-lane LDS handoff defined:
// prevents IR passes and the machine scheduler from reordering LDS ops across
// it (HW LDS pipeline is in-order per wave, so no runtime sync is needed).
__device__ __forceinline__ void lds_fence() {
    asm volatile("" ::: "memory");
#if __has_builtin(__builtin_amdgcn_wave_barrier)
    __builtin_amdgcn_wave_barrier();
#else
    __builtin_amdgcn_sched_barrier(0);
#endif
    asm volatile("" ::: "memory");
}

__device__ __forceinline__ void bfsplit2(float a, float b, unsigned& hi, unsigned& lo) {
    unsigned ua = __float_as_uint(a), ub = __float_as_uint(b);
    hi = (ua >> 16) | (ub & 0xffff0000u);
    float ra = a - __uint_as_float(ua & 0xffff0000u);
    float rb = b - __uint_as_float(ub & 0xffff0000u);
    lo = (__float_as_uint(ra) >> 16) | (__float_as_uint(rb) & 0xffff0000u);
}

__device__ __forceinline__ f32x4 mfma16(short8 a, short8 b, f32x4 c) {
    return __builtin_amdgcn_mfma_f32_16x16x32_bf16(a, b, c, 0, 0, 0);
}

__device__ __forceinline__ short8 s8zero() {
    S8u t; t.u[0] = 0; t.u[1] = 0; t.u[2] = 0; t.u[3] = 0; return t.v;
}

__device__ __forceinline__ void packfrag(f32x4 f0, f32x4 f1, short8& h, short8& l) {
    S8u th, tl;
    bfsplit2(f0[0], f0[1], th.u[0], tl.u[0]);
    bfsplit2(f0[2], f0[3], th.u[1], tl.u[1]);
    bfsplit2(f1[0], f1[1], th.u[2], tl.u[2]);
    bfsplit2(f1[2], f1[3], th.u[3], tl.u[3]);
    h = th.v; l = tl.v;
}

__device__ __forceinline__ void split1(float v, short& h, short& l) {
    unsigned ua = __float_as_uint(v);
    float rv = v - __uint_as_float(ua & 0xffff0000u);
    h = (short)(ua >> 16);
    l = (short)(__float_as_uint(rv) >> 16);
}

// ---------------- kernel 1: hyper-weights wv (latent einsum + LN) ----------------
__global__ void wv_kernel(
    const float* __restrict__ latent,
    const float* __restrict__ pw0, const float* __restrict__ pb0,
    const float* __restrict__ lnw0, const float* __restrict__ lnb0,
    const float* __restrict__ pw1, const float* __restrict__ pb1,
    const float* __restrict__ lnw1, const float* __restrict__ lnb1,
    const float* __restrict__ pw2, const float* __restrict__ pb2,
    const float* __restrict__ lnw2, const float* __restrict__ lnb2,
    const float* __restrict__ pw3, const float* __restrict__ pb3,
    const float* __restrict__ lnw3, const float* __restrict__ lnb3,
    float* __restrict__ wvb) {
    int blk = blockIdx.x;
    int l = blk >> 8;
    int rest = blk & 255;
    int b = rest >> 4, o = rest & 15;
    int c = threadIdx.x;

    const float *pw, *pb, *lnw, *lnb;
    float* outp;
    int ch;
    switch (l) {
        case 0:  pw = pw0; pb = pb0; lnw = lnw0; lnb = lnb0; outp = wvb;                 ch = 62; break;
        case 1:  pw = pw1; pb = pb1; lnw = lnw1; lnb = lnb1; outp = wvb + 15872;         ch = 16; break;
        case 2:  pw = pw2; pb = pb2; lnw = lnw2; lnb = lnb2; outp = wvb + 15872 + 4096;  ch = 16; break;
        default: pw = pw3; pb = pb3; lnw = lnw3; lnb = lnb3; outp = wvb + 15872 + 8192;  ch = 16; break;
    }
    const float* lat = latent + ((size_t)(b * 64 + l * 16 + o)) * 64;
    float dot = 0.f;
    if (c < ch) {
        const float* pr = pw + ((size_t)(o * ch + c)) * 64;
        #pragma unroll
        for (int d0 = 0; d0 < 64; d0++) dot += lat[d0] * pr[d0];
    }
    float act = (c < ch) ? dot : 0.f;
    float mu = wave_sum(act) * (1.0f / ch);
    float diff = (c < ch) ? (dot - mu) : 0.f;
    float var = wave_sum(diff * diff) * (1.0f / ch);
    float norm = diff * rsqrtf(var + 1e-5f);
    if (c < ch) outp[(size_t)(b * 16 + o) * ch + c] = norm * lnw[c] + lnb[c] + pb[o * ch + c];
}

// ---------------- kernel 1b: posenc precompute, pre-split bf16 hi/lo in frag-chunk layout ----
__global__ __launch_bounds__(256) void posenc_pre(
    const float* __restrict__ xg, short* __restrict__ peh, short* __restrict__ pel) {
    int p = blockIdx.x * 256 + threadIdx.x;
    float x0 = xg[2 * p], x1 = xg[2 * p + 1];
    size_t pbs = (size_t)(p >> 4) * 1024 + (size_t)(p & 15) * 8;
    #pragma unroll
    for (int c = 0; c < 8; ++c) {
        float pf[8];
        #pragma unroll
        for (int j = 0; j < 8; ++j) {
            float v;
            if (c < 4) {
                int f = 8 * c + j;
                int idx2 = f - 2;
                int s = idx2 >> 1;
                float sc = __uint_as_float((unsigned)(127 + s) << 23);
                float xa = (idx2 & 1) ? x1 : x0;
                v = sinf(xa * sc);
                if (f == 0) v = x0;
                if (f == 1) v = x1;
            } else {
                int t = 8 * (c - 4) + j;
                int s = t >> 1;
                float sc = __uint_as_float((unsigned)(127 + s) << 23);
                float xa = (t & 1) ? x1 : x0;
                v = sinf(fmaf(xa, sc, PIO2F));
                if (t >= 30) v = 0.f;
            }
            pf[j] = v;
        }
        f32x4 f0 = {pf[0], pf[1], pf[2], pf[3]};
        f32x4 f1 = {pf[4], pf[5], pf[6], pf[7]};
        short8 h, l;
        packfrag(f0, f1, h, l);
        *(short8*)(peh + pbs + c * 128) = h;
        *(short8*)(pel + pbs + c * 128) = l;
    }
}

// ---------------- LDS layout (bytes), total 80960 -> 2 blocks/CU ----------------
#define BOUNCE_OFF  0            // f32 8 x [16][36]   18432
#define W2H_OFF     18432        // short [112][104]   23296
#define W2L_OFF     41728        // short [112][104]   23296
#define W1H_OFF     65024        // short [112][16]     3584
#define W1L_OFF     68608        // short [112][16]     3584
#define B1_OFF      72192        // f32 [112]            448
#define B2_OFF      72640        // f32 [112]            448
#define W3_OFF      73088        // f32 [112]            448
#define WV0H_OFF    73536        // short [16][64]      2048
#define WV0L_OFF    75584        // short [16][64]      2048
#define WVH_OFF     77632        // short [3][16][16]   1536
#define WVL_OFF     79168        // short [3][16][16]   1536
#define MB_LDS_OFF  80704        // f32 [4][16]          256
#define LDS_TOTAL   80960

// ---------------- kernel 2: full per-point pipeline on MFMA ----------------
template <bool PRE>
__global__ __launch_bounds__(512, 2) void mfma_kernel(
    const float* __restrict__ xg,
    const short* __restrict__ peh, const short* __restrict__ pel,
    const float* __restrict__ wvb,
    const float* __restrict__ mb0, const float* __restrict__ mb1,
    const float* __restrict__ mb2, const float* __restrict__ mb3,
    const float* __restrict__ w1, const float* __restrict__ b1,
    const float* __restrict__ w2, const float* __restrict__ b2,
    const float* __restrict__ w3, const float* __restrict__ b3,
    float* __restrict__ out) {
    extern __shared__ char smem[];
    float* lds_bounce = (float*)(smem + BOUNCE_OFF);
    short* lds_w2h    = (short*)(smem + W2H_OFF);
    short* lds_w2l    = (short*)(smem + W2L_OFF);
    short* lds_w1h    = (short*)(smem + W1H_OFF);
    short* lds_w1l    = (short*)(smem + W1L_OFF);
    float* lds_b1     = (float*)(smem + B1_OFF);
    float* lds_b2     = (float*)(smem + B2_OFF);
    float* lds_w3     = (float*)(smem + W3_OFF);
    short* lds_wv0h   = (short*)(smem + WV0H_OFF);
    short* lds_wv0l   = (short*)(smem + WV0L_OFF);
    short* lds_wvh    = (short*)(smem + WVH_OFF);
    short* lds_wvl    = (short*)(smem + WVL_OFF);
    float* lds_mb     = (float*)(smem + MB_LDS_OFF);

    const int b  = blockIdx.x >> 6;
    const int p0 = (blockIdx.x & 63) * 512;

    for (int idx = threadIdx.x; idx < 112 * 104; idx += 512) {
        int o = idx / 104, k = idx - o * 104;
        float v = (o < 100 && k < 100) ? w2[o * 100 + k] : 0.f;
        split1(v, lds_w2h[idx], lds_w2l[idx]);
    }
    for (int idx = threadIdx.x; idx < 112 * 16; idx += 512) {
        int o = idx >> 4;
        float v = (o < 100) ? w1[idx] : 0.f;
        split1(v, lds_w1h[idx], lds_w1l[idx]);
    }
    const float* wv0g = wvb + b * 992;                 // [16][62]
    for (int idx = threadIdx.x; idx < 16 * 64; idx += 512) {
        int o = idx >> 6, k = idx & 63;
        float v = (k < 62) ? wv0g[o * 62 + k] : 0.f;
        split1(v, lds_wv0h[idx], lds_wv0l[idx]);
    }
    const float* wv1g = wvb + 15872 + b * 256;
    const float* wv2g = wvb + 15872 + 4096 + b * 256;
    const float* wv3g = wvb + 15872 + 8192 + b * 256;
    for (int idx = threadIdx.x; idx < 3 * 256; idx += 512) {
        int li = idx >> 8, rest = idx & 255;
        const float* src = (li == 0) ? wv1g : (li == 1) ? wv2g : wv3g;
        split1(src[rest], lds_wvh[idx], lds_wvl[idx]);
    }
    if (threadIdx.x < 112) {
        int o = threadIdx.x;
        lds_b1[o] = (o < 100) ? b1[o] : 0.f;
        lds_b2[o] = (o < 100) ? b2[o] : 0.f;
        lds_w3[o] = (o < 100) ? w3[o] : 0.f;
    }
    if (threadIdx.x >= 128 && threadIdx.x < 192) {
        int t = threadIdx.x - 128;
        int li = t >> 4, o = t & 15;
        const float* mbp = (li == 0) ? mb0 : (li == 1) ? mb1 : (li == 2) ? mb2 : mb3;
        lds_mb[t] = mbp[o];
    }
    __syncthreads();

    const int l    = threadIdx.x & 63;
    const int w    = threadIdx.x >> 6;
    const int lrow = l & 15;   // point-col (B) / out-row (A,C)
    const int lkg  = l >> 4;   // k-group
    float* bwave = lds_bounce + w * (16 * 36);
    const int pbase = w * 64;
    const float b3v = b3[0];
    const f32x4 FZ = {0.f, 0.f, 0.f, 0.f};
    const int ptg0 = (p0 + pbase) >> 4;

    #pragma unroll 1
    for (int pt = 0; pt < 4; ++pt) {
        const int pcol = p0 + pbase + pt * 16 + lrow;

        // ---- posenc frags ----
        short8 pb0h, pb0l, pb1h, pb1l;
        if (PRE) {
            size_t base = (size_t)(ptg0 + pt) * 1024 + (size_t)lkg * 128 + (size_t)lrow * 8;
            pb0h = *(const short8*)(peh + base);
            pb0l = *(const short8*)(pel + base);
            pb1h = *(const short8*)(peh + base + 512);
            pb1l = *(const short8*)(pel + base + 512);
        } else {
            const float x0 = xg[2 * pcol], x1 = xg[2 * pcol + 1];
            float pf[8];
            #pragma unroll
            for (int j = 0; j < 8; ++j) {
                int idx2 = 8 * lkg + j - 2;
                int s = idx2 >> 1;
                float sc = __uint_as_float((unsigned)(127 + s) << 23);
                float xa = (idx2 & 1) ? x1 : x0;
                float v = sinf(xa * sc);
                if (lkg == 0 && j == 0) v = x0;
                if (lkg == 0 && j == 1) v = x1;
                pf[j] = v;
            }
            { f32x4 f0 = {pf[0], pf[1], pf[2], pf[3]};
              f32x4 f1 = {pf[4], pf[5], pf[6], pf[7]};
              packfrag(f0, f1, pb0h, pb0l); }
            #pragma unroll
            for (int j = 0; j < 8; ++j) {
                int t = 8 * lkg + j;
                int s = t >> 1;
                float sc = __uint_as_float((unsigned)(127 + s) << 23);
                float xa = (t & 1) ? x1 : x0;
                float v = sinf(fmaf(xa, sc, PIO2F));
                if (t >= 30) v = 0.f;
                pf[j] = v;
            }
            { f32x4 f0 = {pf[0], pf[1], pf[2], pf[3]};
              f32x4 f1 = {pf[4], pf[5], pf[6], pf[7]};
              packfrag(f0, f1, pb1h, pb1l); }
        }

        // ---- layer 0: K=64 (2 k-steps x 3 terms) ----
        f32x4 acc;
        #pragma unroll
        for (int r = 0; r < 4; ++r) acc[r] = lds_mb[lkg * 4 + r];
        {
            short8 ah = *(const short8*)(lds_wv0h + lrow * 64 + lkg * 8);
            short8 al = *(const short8*)(lds_wv0l + lrow * 64 + lkg * 8);
            acc = mfma16(ah, pb0h, acc);
            acc = mfma16(ah, pb0l, acc);
            acc = mfma16(al, pb0h, acc);
            ah = *(const short8*)(lds_wv0h + lrow * 64 + 32 + lkg * 8);
            al = *(const short8*)(lds_wv0l + lrow * 64 + 32 + lkg * 8);
            acc = mfma16(ah, pb1h, acc);
            acc = mfma16(ah, pb1l, acc);
            acc = mfma16(al, pb1h, acc);
        }

        // ---- layers 1..3: K=16, MFMA->silu->bounce->refrag (fenced handoffs) ----
        short8 fh, fl;
        #pragma unroll
        for (int li = 0; li < 3; ++li) {
            f32x4 sv;
            #pragma unroll
            for (int r = 0; r < 4; ++r) sv[r] = silu_f(acc[r]);
            lds_fence();                                   // prev read -> this write
            *(f32x4*)(bwave + lrow * 36 + lkg * 4) = sv;
            lds_fence();                                   // write -> cross-lane read
            {
                const float* s2 = bwave + lrow * 36 + 8 * (lkg & 1);
                f32x4 f0 = *(const f32x4*)s2;
                f32x4 f1 = *(const f32x4*)(s2 + 4);
                if (lkg >= 2) { f0 = FZ; f1 = FZ; }
                packfrag(f0, f1, fh, fl);
            }
            #pragma unroll
            for (int r = 0; r < 4; ++r) acc[r] = lds_mb[(li + 1) * 16 + lkg * 4 + r];
            short8 ah = *(const short8*)(lds_wvh + (li * 16 + lrow) * 16 + (lkg & 1) * 8);
            short8 al = *(const short8*)(lds_wvl + (li * 16 + lrow) * 16 + (lkg & 1) * 8);
            if (lkg >= 2) { ah = s8zero(); al = s8zero(); }
            acc = mfma16(ah, fh, acc);
            acc = mfma16(ah, fl, acc);
            acc = mfma16(al, fh, acc);
        }
        // hb = silu(layer3) -> bounce -> hb frag
        {
            f32x4 sv;
            #pragma unroll
            for (int r = 0; r < 4; ++r) sv[r] = silu_f(acc[r]);
            lds_fence();
            *(f32x4*)(bwave + lrow * 36 + lkg * 4) = sv;
            lds_fence();
        }
        short8 hbh, hbl;
        {
            const float* s2 = bwave + lrow * 36 + 8 * (lkg & 1);
            f32x4 f0 = *(const f32x4*)s2;
            f32x4 f1 = *(const f32x4*)(s2 + 4);
            if (lkg >= 2) { f0 = FZ; f1 = FZ; }
            packfrag(f0, f1, hbh, hbl);
        }

        // ---- w1 interleaved with w2 per k-slice; a2[7] accumulates across ks ----
        f32x4 a2[7];
        #pragma unroll
        for (int f2 = 0; f2 < 7; ++f2) {
            #pragma unroll
            for (int r = 0; r < 4; ++r) a2[f2][r] = lds_b2[f2 * 16 + lkg * 4 + r];
        }
        #pragma unroll
        for (int ks = 0; ks < 4; ++ks) {
            lds_fence();                                   // prev h2 read -> these writes
            #pragma unroll
            for (int lf = 0; lf < 2; ++lf) {
                const int fmt = 2 * ks + lf;
                if (fmt < 7) {
                    f32x4 a1;
                    #pragma unroll
                    for (int r = 0; r < 4; ++r) a1[r] = lds_b1[fmt * 16 + lkg * 4 + r];
                    short8 ah = *(const short8*)(lds_w1h + (fmt * 16 + lrow) * 16 + (lkg & 1) * 8);
                    short8 al = *(const short8*)(lds_w1l + (fmt * 16 + lrow) * 16 + (lkg & 1) * 8);
                    if (lkg >= 2) { ah = s8zero(); al = s8zero(); }
                    a1 = mfma16(ah, hbh, a1);
                    a1 = mfma16(ah, hbl, a1);
                    a1 = mfma16(al, hbh, a1);
                    f32x4 sv;
                    #pragma unroll
                    for (int r = 0; r < 4; ++r) sv[r] = silu_f(a1[r]);
                    *(f32x4*)(bwave + lrow * 36 + lf * 16 + lkg * 4) = sv;
                }
            }
            lds_fence();                                   // writes -> cross-lane read
            const int kb = ks * 32 + lkg * 8;
            const bool act = kb < 104;
            const float* s2 = bwave + lrow * 36 + lkg * 8;
            f32x4 f0 = *(const f32x4*)s2;
            f32x4 f1 = *(const f32x4*)(s2 + 4);
            if (!act) { f0 = FZ; f1 = FZ; }
            short8 h2h, h2l;
            packfrag(f0, f1, h2h, h2l);
            const int kba = act ? kb : 0;
            #pragma unroll
            for (int f2 = 0; f2 < 7; ++f2) {
                short8 ah = *(const short8*)(lds_w2h + (f2 * 16 + lrow) * 104 + kba);
                short8 al = *(const short8*)(lds_w2l + (f2 * 16 + lrow) * 104 + kba);
                if (!act) { ah = s8zero(); al = s8zero(); }
                a2[f2] = mfma16(ah, h2h, a2[f2]);
                a2[f2] = mfma16(ah, h2l, a2[f2]);
                a2[f2] = mfma16(al, h2h, a2[f2]);
            }
        }

        // ---- fused silu/w3 epilogue + cross-lane-group reduce ----
        float outv = 0.f;
        #pragma unroll
        for (int f2 = 0; f2 < 7; ++f2) {
            #pragma unroll
            for (int r = 0; r < 4; ++r)
                outv = fmaf(silu_f(a2[f2][r]), lds_w3[f2 * 16 + lkg * 4 + r], outv);
        }
        outv += __shfl_xor(outv, 16, 64);
        outv += __shfl_xor(outv, 32, 64);
        if (l < 16)
            out[(size_t)b * N_PTS + pcol] = outv + b3v;
    }
}

// ---------------- launcher ----------------
extern "C" void kernel_launch(void* const* d_in, const int* in_sizes, int n_in,
                              void* d_out, int out_size, void* d_ws, size_t ws_size,
                              hipStream_t stream) {
    const float* x = (const float*)d_in[0];
    const float* latent = (const float*)d_in[1];
    const float *pw[4], *pb[4], *lnw[4], *lnb[4], *mb[4];
    for (int l = 0; l < 4; l++) {
        pw[l]  = (const float*)d_in[2 + 5 * l];
        pb[l]  = (const float*)d_in[3 + 5 * l];
        lnw[l] = (const float*)d_in[4 + 5 * l];
        lnb[l] = (const float*)d_in[5 + 5 * l];
        mb[l]  = (const float*)d_in[6 + 5 * l];
    }
    const float* w1 = (const float*)d_in[22];
    const float* b1 = (const float*)d_in[23];
    const float* w2 = (const float*)d_in[24];
    const float* b2 = (const float*)d_in[25];
    const float* w3 = (const float*)d_in[26];
    const float* b3 = (const float*)d_in[27];

    float* wvb = (float*)d_ws;                       // 28160 f32 = 112640 B
    short* peh = (short*)((char*)d_ws + 112640);     // 4 MB
    short* pel = peh + (size_t)N_PTS * 64;           // 4 MB
    const size_t WS_NEED = 112640 + 2 * (size_t)N_PTS * 64 * sizeof(short);
    bool pre = ws_size >= WS_NEED;

    wv_kernel<<<1024, 64, 0, stream>>>(latent,
        pw[0], pb[0], lnw[0], lnb[0],
        pw[1], pb[1], lnw[1], lnb[1],
        pw[2], pb[2], lnw[2], lnb[2],
        pw[3], pb[3], lnw[3], lnb[3],
        wvb);

    if (pre) {
        posenc_pre<<<N_PTS / 256, 256, 0, stream>>>(x, peh, pel);
        hipFuncSetAttribute((const void*)mfma_kernel<true>,
                            hipFuncAttributeMaxDynamicSharedMemorySize, LDS_TOTAL);
        mfma_kernel<true><<<BATCH * (N_PTS / 512), 512, LDS_TOTAL, stream>>>(
            x, peh, pel, wvb, mb[0], mb[1], mb[2], mb[3],
            w1, b1, w2, b2, w3, b3, (float*)d_out);
    } else {
        hipFuncSetAttribute((const void*)mfma_kernel<false>,
                            hipFuncAttributeMaxDynamicSharedMemorySize, LDS_TOTAL);
        mfma_kernel<false><<<BATCH * (N_PTS / 512), 512, LDS_TOTAL, stream>>>(
            x, peh, pel, wvb, mb[0], mb[1], mb[2], mb[3],
            w1, b1, w2, b2, w3, b3, (float*)d_out);
    }
}

// Round 13
// 91.804 us; speedup vs baseline: 3.2120x; 1.2127x over previous
//
#include <hip/hip_runtime.h>

#define N_PTS 32768
#define BATCH 16
#define PIO2F 1.5707963705062866f

// ---------------- types / helpers ----------------
typedef __attribute__((ext_vector_type(8))) _Float16 half8;
typedef __attribute__((ext_vector_type(4))) _Float16 half4;
typedef __attribute__((ext_vector_type(4))) float f32x4;

__device__ __forceinline__ float silu_f(float v) {
    return v * __builtin_amdgcn_rcpf(1.0f + __expf(-v));
}

__device__ __forceinline__ float wave_sum(float v) {
    #pragma unroll
    for (int off = 1; off < 64; off <<= 1) v += __shfl_xor(v, off, 64);
    return v;
}

// Free compile-time fence: makes intra-wave cross-lane LDS handoff defined
// (R11 lesson: without it the scheduler reorders ds_write vs cross-lane ds_read).
__device__ __forceinline__ void lds_fence() {
    asm volatile("" ::: "memory");
#if __has_builtin(__builtin_amdgcn_wave_barrier)
    __builtin_amdgcn_wave_barrier();
#else
    __builtin_amdgcn_sched_barrier(0);
#endif
    asm volatile("" ::: "memory");
}

__device__ __forceinline__ f32x4 mfma16h(half8 a, half8 b, f32x4 c) {
    return __builtin_amdgcn_mfma_f32_16x16x32_f16(a, b, c, 0, 0, 0);
}

__device__ __forceinline__ half8 h8zero() {
    half8 z;
    #pragma unroll
    for (int r = 0; r < 8; ++r) z[r] = (_Float16)0.0f;
    return z;
}

// split one f32 into hi/lo f16 (hi = RNE cast; lo = remainder)
__device__ __forceinline__ void split1h(float v, _Float16& h, _Float16& l) {
    _Float16 hh = (_Float16)v;
    h = hh;
    l = (_Float16)(v - (float)hh);
}

// ---------------- kernel 1: hyper-weights wv (latent einsum + LN) ----------------
__global__ void wv_kernel(
    const float* __restrict__ latent,
    const float* __restrict__ pw0, const float* __restrict__ pb0,
    const float* __restrict__ lnw0, const float* __restrict__ lnb0,
    const float* __restrict__ pw1, const float* __restrict__ pb1,
    const float* __restrict__ lnw1, const float* __restrict__ lnb1,
    const float* __restrict__ pw2, const float* __restrict__ pb2,
    const float* __restrict__ lnw2, const float* __restrict__ lnb2,
    const float* __restrict__ pw3, const float* __restrict__ pb3,
    const float* __restrict__ lnw3, const float* __restrict__ lnb3,
    float* __restrict__ wvb) {
    int blk = blockIdx.x;
    int l = blk >> 8;
    int rest = blk & 255;
    int b = rest >> 4, o = rest & 15;
    int c = threadIdx.x;

    const float *pw, *pb, *lnw, *lnb;
    float* outp;
    int ch;
    switch (l) {
        case 0:  pw = pw0; pb = pb0; lnw = lnw0; lnb = lnb0; outp = wvb;                 ch = 62; break;
        case 1:  pw = pw1; pb = pb1; lnw = lnw1; lnb = lnb1; outp = wvb + 15872;         ch = 16; break;
        case 2:  pw = pw2; pb = pb2; lnw = lnw2; lnb = lnb2; outp = wvb + 15872 + 4096;  ch = 16; break;
        default: pw = pw3; pb = pb3; lnw = lnw3; lnb = lnb3; outp = wvb + 15872 + 8192;  ch = 16; break;
    }
    const float* lat = latent + ((size_t)(b * 64 + l * 16 + o)) * 64;
    float dot = 0.f;
    if (c < ch) {
        const float* pr = pw + ((size_t)(o * ch + c)) * 64;
        #pragma unroll
        for (int d0 = 0; d0 < 64; d0++) dot += lat[d0] * pr[d0];
    }
    float act = (c < ch) ? dot : 0.f;
    float mu = wave_sum(act) * (1.0f / ch);
    float diff = (c < ch) ? (dot - mu) : 0.f;
    float var = wave_sum(diff * diff) * (1.0f / ch);
    float norm = diff * rsqrtf(var + 1e-5f);
    if (c < ch) outp[(size_t)(b * 16 + o) * ch + c] = norm * lnw[c] + lnb[c] + pb[o * ch + c];
}

// ---------------- kernel 1b: posenc precompute, single-f16 in frag-chunk layout ----
// chunk c (8 feats: c<4 -> frag0 feats 8c..8c+7; c>=4 -> frag1) stored at
// f16[ ((p>>4)*8 + c)*128 + (p&15)*8 ]
__global__ __launch_bounds__(256) void posenc_pre(
    const float* __restrict__ xg, _Float16* __restrict__ peh) {
    int p = blockIdx.x * 256 + threadIdx.x;
    float x0 = xg[2 * p], x1 = xg[2 * p + 1];
    size_t pbs = (size_t)(p >> 4) * 1024 + (size_t)(p & 15) * 8;
    #pragma unroll
    for (int c = 0; c < 8; ++c) {
        half8 hv;
        #pragma unroll
        for (int j = 0; j < 8; ++j) {
            float v;
            if (c < 4) {
                int f = 8 * c + j;
                int idx2 = f - 2;
                int s = idx2 >> 1;
                float sc = __uint_as_float((unsigned)(127 + s) << 23);
                float xa = (idx2 & 1) ? x1 : x0;
                v = sinf(xa * sc);
                if (f == 0) v = x0;
                if (f == 1) v = x1;
            } else {
                int t = 8 * (c - 4) + j;
                int s = t >> 1;
                float sc = __uint_as_float((unsigned)(127 + s) << 23);
                float xa = (t & 1) ? x1 : x0;
                v = sinf(fmaf(xa, sc, PIO2F));
                if (t >= 30) v = 0.f;
            }
            hv[j] = (_Float16)v;
        }
        *(half8*)(peh + pbs + c * 128) = hv;
    }
}

// ---------------- LDS layout (bytes), total 72768 -> 2 blocks/CU ----------------
#define BOUNCE_OFF  0            // f16 8 x [16][40]   10240
#define W2H_OFF     10240        // f16 [112][104]     23296
#define W2L_OFF     33536        // f16 [112][104]     23296
#define W1H_OFF     56832        // f16 [112][16]       3584
#define W1L_OFF     60416        // f16 [112][16]       3584
#define B1_OFF      64000        // f32 [112]            448
#define B2_OFF      64448        // f32 [112]            448
#define W3_OFF      64896        // f32 [112]            448
#define WV0H_OFF    65344        // f16 [16][64]        2048
#define WV0L_OFF    67392        // f16 [16][64]        2048
#define WVH_OFF     69440        // f16 [3][16][16]     1536
#define WVL_OFF     70976        // f16 [3][16][16]     1536
#define MB_LDS_OFF  72512        // f32 [4][16]          256
#define LDS_TOTAL   72768

// ---------------- kernel 2: full per-point pipeline on MFMA (fp16 datapath) ----------------
// weights 2-term f16 (hi+lo), activations 1-term f16; bounce buffer stores f16
// so the cross-lane read IS the MFMA fragment (no packfrag anywhere).
template <bool PRE>
__global__ __launch_bounds__(512, 2) void mfma_kernel(
    const float* __restrict__ xg,
    const _Float16* __restrict__ peh,
    const float* __restrict__ wvb,
    const float* __restrict__ mb0, const float* __restrict__ mb1,
    const float* __restrict__ mb2, const float* __restrict__ mb3,
    const float* __restrict__ w1, const float* __restrict__ b1,
    const float* __restrict__ w2, const float* __restrict__ b2,
    const float* __restrict__ w3, const float* __restrict__ b3,
    float* __restrict__ out) {
    extern __shared__ char smem[];
    _Float16* lds_bounce = (_Float16*)(smem + BOUNCE_OFF);
    _Float16* lds_w2h    = (_Float16*)(smem + W2H_OFF);
    _Float16* lds_w2l    = (_Float16*)(smem + W2L_OFF);
    _Float16* lds_w1h    = (_Float16*)(smem + W1H_OFF);
    _Float16* lds_w1l    = (_Float16*)(smem + W1L_OFF);
    float*    lds_b1     = (float*)(smem + B1_OFF);
    float*    lds_b2     = (float*)(smem + B2_OFF);
    float*    lds_w3     = (float*)(smem + W3_OFF);
    _Float16* lds_wv0h   = (_Float16*)(smem + WV0H_OFF);
    _Float16* lds_wv0l   = (_Float16*)(smem + WV0L_OFF);
    _Float16* lds_wvh    = (_Float16*)(smem + WVH_OFF);
    _Float16* lds_wvl    = (_Float16*)(smem + WVL_OFF);
    float*    lds_mb     = (float*)(smem + MB_LDS_OFF);

    const int b  = blockIdx.x >> 6;
    const int p0 = (blockIdx.x & 63) * 512;

    // ---- stage shared weights (hi/lo f16 split) ----
    for (int idx = threadIdx.x; idx < 112 * 104; idx += 512) {
        int o = idx / 104, k = idx - o * 104;
        float v = (o < 100 && k < 100) ? w2[o * 100 + k] : 0.f;
        split1h(v, lds_w2h[idx], lds_w2l[idx]);
    }
    for (int idx = threadIdx.x; idx < 112 * 16; idx += 512) {
        int o = idx >> 4;
        float v = (o < 100) ? w1[idx] : 0.f;
        split1h(v, lds_w1h[idx], lds_w1l[idx]);
    }
    const float* wv0g = wvb + b * 992;                 // [16][62]
    for (int idx = threadIdx.x; idx < 16 * 64; idx += 512) {
        int o = idx >> 6, k = idx & 63;
        float v = (k < 62) ? wv0g[o * 62 + k] : 0.f;
        split1h(v, lds_wv0h[idx], lds_wv0l[idx]);
    }
    const float* wv1g = wvb + 15872 + b * 256;
    const float* wv2g = wvb + 15872 + 4096 + b * 256;
    const float* wv3g = wvb + 15872 + 8192 + b * 256;
    for (int idx = threadIdx.x; idx < 3 * 256; idx += 512) {
        int li = idx >> 8, rest = idx & 255;
        const float* src = (li == 0) ? wv1g : (li == 1) ? wv2g : wv3g;
        split1h(src[rest], lds_wvh[idx], lds_wvl[idx]);
    }
    if (threadIdx.x < 112) {
        int o = threadIdx.x;
        lds_b1[o] = (o < 100) ? b1[o] : 0.f;
        lds_b2[o] = (o < 100) ? b2[o] : 0.f;
        lds_w3[o] = (o < 100) ? w3[o] : 0.f;
    }
    if (threadIdx.x >= 128 && threadIdx.x < 192) {
        int t = threadIdx.x - 128;
        int li = t >> 4, o = t & 15;
        const float* mbp = (li == 0) ? mb0 : (li == 1) ? mb1 : (li == 2) ? mb2 : mb3;
        lds_mb[t] = mbp[o];
    }
    __syncthreads();

    const int l    = threadIdx.x & 63;
    const int w    = threadIdx.x >> 6;
    const int lrow = l & 15;   // point-col (B) / out-row (A,C)
    const int lkg  = l >> 4;   // k-group
    _Float16* bwave = lds_bounce + w * (16 * 40);
    const int pbase = w * 64;
    const float b3v = b3[0];
    const int ptg0 = (p0 + pbase) >> 4;

    #pragma unroll 1
    for (int pt = 0; pt < 4; ++pt) {
        const int pcol = p0 + pbase + pt * 16 + lrow;

        // ---- posenc B-frags (single f16) ----
        half8 pb0, pb1;
        if (PRE) {
            size_t base = (size_t)(ptg0 + pt) * 1024 + (size_t)lkg * 128 + (size_t)lrow * 8;
            pb0 = *(const half8*)(peh + base);
            pb1 = *(const half8*)(peh + base + 512);
        } else {
            const float x0 = xg[2 * pcol], x1 = xg[2 * pcol + 1];
            #pragma unroll
            for (int j = 0; j < 8; ++j) {
                int idx2 = 8 * lkg + j - 2;
                int s = idx2 >> 1;
                float sc = __uint_as_float((unsigned)(127 + s) << 23);
                float xa = (idx2 & 1) ? x1 : x0;
                float v = sinf(xa * sc);
                if (lkg == 0 && j == 0) v = x0;
                if (lkg == 0 && j == 1) v = x1;
                pb0[j] = (_Float16)v;
            }
            #pragma unroll
            for (int j = 0; j < 8; ++j) {
                int t = 8 * lkg + j;
                int s = t >> 1;
                float sc = __uint_as_float((unsigned)(127 + s) << 23);
                float xa = (t & 1) ? x1 : x0;
                float v = sinf(fmaf(xa, sc, PIO2F));
                if (t >= 30) v = 0.f;
                pb1[j] = (_Float16)v;
            }
        }

        // ---- layer 0: K=64 (2 k-steps x 2 terms) ----
        f32x4 acc;
        #pragma unroll
        for (int r = 0; r < 4; ++r) acc[r] = lds_mb[lkg * 4 + r];
        {
            half8 ah = *(const half8*)(lds_wv0h + lrow * 64 + lkg * 8);
            half8 al = *(const half8*)(lds_wv0l + lrow * 64 + lkg * 8);
            acc = mfma16h(ah, pb0, acc);
            acc = mfma16h(al, pb0, acc);
            ah = *(const half8*)(lds_wv0h + lrow * 64 + 32 + lkg * 8);
            al = *(const half8*)(lds_wv0l + lrow * 64 + 32 + lkg * 8);
            acc = mfma16h(ah, pb1, acc);
            acc = mfma16h(al, pb1, acc);
        }

        // ---- layers 1..3: K=16; silu -> f16 bounce -> direct frag read ----
        #pragma unroll
        for (int li = 0; li < 3; ++li) {
            half4 hv;
            #pragma unroll
            for (int r = 0; r < 4; ++r) hv[r] = (_Float16)silu_f(acc[r]);
            lds_fence();                                   // prev read -> this write
            *(half4*)(bwave + lrow * 40 + lkg * 4) = hv;
            lds_fence();                                   // write -> cross-lane read
            half8 f = *(const half8*)(bwave + lrow * 40 + (lkg & 1) * 8);
            #pragma unroll
            for (int r = 0; r < 4; ++r) acc[r] = lds_mb[(li + 1) * 16 + lkg * 4 + r];
            half8 ah = *(const half8*)(lds_wvh + (li * 16 + lrow) * 16 + (lkg & 1) * 8);
            half8 al = *(const half8*)(lds_wvl + (li * 16 + lrow) * 16 + (lkg & 1) * 8);
            if (lkg >= 2) { ah = h8zero(); al = h8zero(); }
            acc = mfma16h(ah, f, acc);
            acc = mfma16h(al, f, acc);
        }
        // hb = silu(layer3) -> bounce -> hb frag
        {
            half4 hv;
            #pragma unroll
            for (int r = 0; r < 4; ++r) hv[r] = (_Float16)silu_f(acc[r]);
            lds_fence();
            *(half4*)(bwave + lrow * 40 + lkg * 4) = hv;
            lds_fence();
        }
        half8 hbf = *(const half8*)(bwave + lrow * 40 + (lkg & 1) * 8);

        // ---- w1 interleaved with w2 per k-slice; a2[7] accumulates across ks ----
        f32x4 a2[7];
        #pragma unroll
        for (int f2 = 0; f2 < 7; ++f2) {
            #pragma unroll
            for (int r = 0; r < 4; ++r) a2[f2][r] = lds_b2[f2 * 16 + lkg * 4 + r];
        }
        #pragma unroll
        for (int ks = 0; ks < 4; ++ks) {
            lds_fence();                                   // prev h2 read -> these writes
            #pragma unroll
            for (int lf = 0; lf < 2; ++lf) {
                const int fmt = 2 * ks + lf;
                if (fmt < 7) {
                    f32x4 a1;
                    #pragma unroll
                    for (int r = 0; r < 4; ++r) a1[r] = lds_b1[fmt * 16 + lkg * 4 + r];
                    half8 ah = *(const half8*)(lds_w1h + (fmt * 16 + lrow) * 16 + (lkg & 1) * 8);
                    half8 al = *(const half8*)(lds_w1l + (fmt * 16 + lrow) * 16 + (lkg & 1) * 8);
                    if (lkg >= 2) { ah = h8zero(); al = h8zero(); }
                    a1 = mfma16h(ah, hbf, a1);
                    a1 = mfma16h(al, hbf, a1);
                    half4 hv;
                    #pragma unroll
                    for (int r = 0; r < 4; ++r) hv[r] = (_Float16)silu_f(a1[r]);
                    *(half4*)(bwave + lrow * 40 + lf * 16 + lkg * 4) = hv;
                }
            }
            lds_fence();                                   // writes -> cross-lane read
            half8 h2f = *(const half8*)(bwave + lrow * 40 + lkg * 8);
            const int kb = ks * 32 + lkg * 8;
            const bool act = kb < 104;
            const int kba = act ? kb : 0;
            #pragma unroll
            for (int f2 = 0; f2 < 7; ++f2) {
                half8 ah = *(const half8*)(lds_w2h + (f2 * 16 + lrow) * 104 + kba);
                half8 al = *(const half8*)(lds_w2l + (f2 * 16 + lrow) * 104 + kba);
                if (!act) { ah = h8zero(); al = h8zero(); }
                a2[f2] = mfma16h(ah, h2f, a2[f2]);
                a2[f2] = mfma16h(al, h2f, a2[f2]);
            }
        }

        // ---- fused silu/w3 epilogue + cross-lane-group reduce ----
        float outv = 0.f;
        #pragma unroll
        for (int f2 = 0; f2 < 7; ++f2) {
            #pragma unroll
            for (int r = 0; r < 4; ++r)
                outv = fmaf(silu_f(a2[f2][r]), lds_w3[f2 * 16 + lkg * 4 + r], outv);
        }
        outv += __shfl_xor(outv, 16, 64);
        outv += __shfl_xor(outv, 32, 64);
        if (l < 16)
            out[(size_t)b * N_PTS + pcol] = outv + b3v;
    }
}

// ---------------- launcher ----------------
extern "C" void kernel_launch(void* const* d_in, const int* in_sizes, int n_in,
                              void* d_out, int out_size, void* d_ws, size_t ws_size,
                              hipStream_t stream) {
    const float* x = (const float*)d_in[0];
    const float* latent = (const float*)d_in[1];
    const float *pw[4], *pb[4], *lnw[4], *lnb[4], *mb[4];
    for (int l = 0; l < 4; l++) {
        pw[l]  = (const float*)d_in[2 + 5 * l];
        pb[l]  = (const float*)d_in[3 + 5 * l];
        lnw[l] = (const float*)d_in[4 + 5 * l];
        lnb[l] = (const float*)d_in[5 + 5 * l];
        mb[l]  = (const float*)d_in[6 + 5 * l];
    }
    const float* w1 = (const float*)d_in[22];
    const float* b1 = (const float*)d_in[23];
    const float* w2 = (const float*)d_in[24];
    const float* b2 = (const float*)d_in[25];
    const float* w3 = (const float*)d_in[26];
    const float* b3 = (const float*)d_in[27];

    float* wvb = (float*)d_ws;                            // 28160 f32 = 112640 B
    _Float16* peh = (_Float16*)((char*)d_ws + 112640);    // 4 MB
    const size_t WS_NEED = 112640 + (size_t)N_PTS * 64 * sizeof(_Float16);
    bool pre = ws_size >= WS_NEED;

    wv_kernel<<<1024, 64, 0, stream>>>(latent,
        pw[0], pb[0], lnw[0], lnb[0],
        pw[1], pb[1], lnw[1], lnb[1],
        pw[2], pb[2], lnw[2], lnb[2],
        pw[3], pb[3], lnw[3], lnb[3],
        wvb);

    if (pre) {
        posenc_pre<<<N_PTS / 256, 256, 0, stream>>>(x, peh);
        hipFuncSetAttribute((const void*)mfma_kernel<true>,
                            hipFuncAttributeMaxDynamicSharedMemorySize, LDS_TOTAL);
        mfma_kernel<true><<<BATCH * (N_PTS / 512), 512, LDS_TOTAL, stream>>>(
            x, peh, wvb, mb[0], mb[1], mb[2], mb[3],
            w1, b1, w2, b2, w3, b3, (float*)d_out);
    } else {
        hipFuncSetAttribute((const void*)mfma_kernel<false>,
                            hipFuncAttributeMaxDynamicSharedMemorySize, LDS_TOTAL);
        mfma_kernel<false><<<BATCH * (N_PTS / 512), 512, LDS_TOTAL, stream>>>(
            x, peh, wvb, mb[0], mb[1], mb[2], mb[3],
            w1, b1, w2, b2, w3, b3, (float*)d_out);
    }
}

// Round 14
// 90.323 us; speedup vs baseline: 3.2647x; 1.0164x over previous
//
#include <hip/hip_runtime.h>

#define N_PTS 32768
#define BATCH 16
#define PIO2F 1.5707963705062866f

// ---------------- types / helpers ----------------
typedef __attribute__((ext_vector_type(8))) _Float16 half8;
typedef __attribute__((ext_vector_type(4))) _Float16 half4;
typedef __attribute__((ext_vector_type(4))) float f32x4;

__device__ __forceinline__ float silu_f(float v) {
    return v * __builtin_amdgcn_rcpf(1.0f + __expf(-v));
}

__device__ __forceinline__ float wave_sum(float v) {
    #pragma unroll
    for (int off = 1; off < 64; off <<= 1) v += __shfl_xor(v, off, 64);
    return v;
}

// Free compile-time fence: makes intra-wave cross-lane LDS handoff defined
// (R11 lesson: without it the scheduler reorders ds_write vs cross-lane ds_read).
__device__ __forceinline__ void lds_fence() {
    asm volatile("" ::: "memory");
#if __has_builtin(__builtin_amdgcn_wave_barrier)
    __builtin_amdgcn_wave_barrier();
#else
    __builtin_amdgcn_sched_barrier(0);
#endif
    asm volatile("" ::: "memory");
}

__device__ __forceinline__ f32x4 mfma16h(half8 a, half8 b, f32x4 c) {
    return __builtin_amdgcn_mfma_f32_16x16x32_f16(a, b, c, 0, 0, 0);
}

// split one f32 into hi/lo f16 (hi = RNE cast; lo = remainder)
__device__ __forceinline__ void split1h(float v, _Float16& h, _Float16& l) {
    _Float16 hh = (_Float16)v;
    h = hh;
    l = (_Float16)(v - (float)hh);
}

// ---------------- kernel 1: hyper-weights wv (latent einsum + LN) ----------------
__global__ void wv_kernel(
    const float* __restrict__ latent,
    const float* __restrict__ pw0, const float* __restrict__ pb0,
    const float* __restrict__ lnw0, const float* __restrict__ lnb0,
    const float* __restrict__ pw1, const float* __restrict__ pb1,
    const float* __restrict__ lnw1, const float* __restrict__ lnb1,
    const float* __restrict__ pw2, const float* __restrict__ pb2,
    const float* __restrict__ lnw2, const float* __restrict__ lnb2,
    const float* __restrict__ pw3, const float* __restrict__ pb3,
    const float* __restrict__ lnw3, const float* __restrict__ lnb3,
    float* __restrict__ wvb) {
    int blk = blockIdx.x;
    int l = blk >> 8;
    int rest = blk & 255;
    int b = rest >> 4, o = rest & 15;
    int c = threadIdx.x;

    const float *pw, *pb, *lnw, *lnb;
    float* outp;
    int ch;
    switch (l) {
        case 0:  pw = pw0; pb = pb0; lnw = lnw0; lnb = lnb0; outp = wvb;                 ch = 62; break;
        case 1:  pw = pw1; pb = pb1; lnw = lnw1; lnb = lnb1; outp = wvb + 15872;         ch = 16; break;
        case 2:  pw = pw2; pb = pb2; lnw = lnw2; lnb = lnb2; outp = wvb + 15872 + 4096;  ch = 16; break;
        default: pw = pw3; pb = pb3; lnw = lnw3; lnb = lnb3; outp = wvb + 15872 + 8192;  ch = 16; break;
    }
    const float* lat = latent + ((size_t)(b * 64 + l * 16 + o)) * 64;
    float dot = 0.f;
    if (c < ch) {
        const float* pr = pw + ((size_t)(o * ch + c)) * 64;
        #pragma unroll
        for (int d0 = 0; d0 < 64; d0++) dot += lat[d0] * pr[d0];
    }
    float act = (c < ch) ? dot : 0.f;
    float mu = wave_sum(act) * (1.0f / ch);
    float diff = (c < ch) ? (dot - mu) : 0.f;
    float var = wave_sum(diff * diff) * (1.0f / ch);
    float norm = diff * rsqrtf(var + 1e-5f);
    if (c < ch) outp[(size_t)(b * 16 + o) * ch + c] = norm * lnw[c] + lnb[c] + pb[o * ch + c];
}

// ---------------- kernel 1b: posenc precompute, single-f16 in frag-chunk layout ----
__global__ __launch_bounds__(256) void posenc_pre(
    const float* __restrict__ xg, _Float16* __restrict__ peh) {
    int p = blockIdx.x * 256 + threadIdx.x;
    float x0 = xg[2 * p], x1 = xg[2 * p + 1];
    size_t pbs = (size_t)(p >> 4) * 1024 + (size_t)(p & 15) * 8;
    #pragma unroll
    for (int c = 0; c < 8; ++c) {
        half8 hv;
        #pragma unroll
        for (int j = 0; j < 8; ++j) {
            float v;
            if (c < 4) {
                int f = 8 * c + j;
                int idx2 = f - 2;
                int s = idx2 >> 1;
                float sc = __uint_as_float((unsigned)(127 + s) << 23);
                float xa = (idx2 & 1) ? x1 : x0;
                v = sinf(xa * sc);
                if (f == 0) v = x0;
                if (f == 1) v = x1;
            } else {
                int t = 8 * (c - 4) + j;
                int s = t >> 1;
                float sc = __uint_as_float((unsigned)(127 + s) << 23);
                float xa = (t & 1) ? x1 : x0;
                v = sinf(fmaf(xa, sc, PIO2F));
                if (t >= 30) v = 0.f;
            }
            hv[j] = (_Float16)v;
        }
        *(half8*)(peh + pbs + c * 128) = hv;
    }
}

// ---------------- LDS layout (bytes), total 80704 -> 2 blocks/CU ----------------
// All strides chosen so every wave access is <=2-way bank aliasing (free),
// and all K-tails are ZERO-FILLED in LDS (no cndmask masking in the hot loop).
#define BOUNCE_OFF  0            // f16 8 x [16][40]   10240
#define W2H_OFF     10240        // f16 [112][120]     26880  (cols 104..119 = 0)
#define W2L_OFF     37120        // f16 [112][120]     26880
#define W1H_OFF     64000        // f16 [112][40]       8960  (cols 16..39 = 0)
#define WV0H_OFF    72960        // f16 [16][72]        2304  (cols 62..71 = 0)
#define WVH_OFF     75264        // f16 [3][16][40]     3840  (cols 16..39 = 0)
#define B1_OFF      79104        // f32 [112]            448
#define B2_OFF      79552        // f32 [112]            448
#define W3_OFF      80000        // f32 [112]            448
#define MB_LDS_OFF  80448        // f32 [4][16]          256
#define LDS_TOTAL   80704

// ---------------- kernel 2: full per-point pipeline on MFMA (fp16 datapath) ----------------
// weights: w2 2-term f16 (hi+lo); hyper layers + w1 single-term f16 (precision
// headroom: output is bf16-quantized at 4.88e-4, threshold 1.494e-3).
template <bool PRE>
__global__ __launch_bounds__(512, 2) void mfma_kernel(
    const float* __restrict__ xg,
    const _Float16* __restrict__ peh,
    const float* __restrict__ wvb,
    const float* __restrict__ mb0, const float* __restrict__ mb1,
    const float* __restrict__ mb2, const float* __restrict__ mb3,
    const float* __restrict__ w1, const float* __restrict__ b1,
    const float* __restrict__ w2, const float* __restrict__ b2,
    const float* __restrict__ w3, const float* __restrict__ b3,
    float* __restrict__ out) {
    extern __shared__ char smem[];
    _Float16* lds_bounce = (_Float16*)(smem + BOUNCE_OFF);
    _Float16* lds_w2h    = (_Float16*)(smem + W2H_OFF);
    _Float16* lds_w2l    = (_Float16*)(smem + W2L_OFF);
    _Float16* lds_w1h    = (_Float16*)(smem + W1H_OFF);
    _Float16* lds_wv0h   = (_Float16*)(smem + WV0H_OFF);
    _Float16* lds_wvh    = (_Float16*)(smem + WVH_OFF);
    float*    lds_b1     = (float*)(smem + B1_OFF);
    float*    lds_b2     = (float*)(smem + B2_OFF);
    float*    lds_w3     = (float*)(smem + W3_OFF);
    float*    lds_mb     = (float*)(smem + MB_LDS_OFF);

    const int b  = blockIdx.x >> 6;
    const int p0 = (blockIdx.x & 63) * 512;

    // ---- stage weights (zero-padded K, hi/lo split only for w2) ----
    for (int idx = threadIdx.x; idx < 112 * 120; idx += 512) {
        int o = idx / 120, k = idx - o * 120;
        float v = (o < 100 && k < 100) ? w2[o * 100 + k] : 0.f;
        split1h(v, lds_w2h[idx], lds_w2l[idx]);
    }
    for (int idx = threadIdx.x; idx < 112 * 40; idx += 512) {
        int o = idx / 40, k = idx - o * 40;
        lds_w1h[idx] = (_Float16)((o < 100 && k < 16) ? w1[o * 16 + k] : 0.f);
    }
    const float* wv0g = wvb + b * 992;                 // [16][62]
    for (int idx = threadIdx.x; idx < 16 * 72; idx += 512) {
        int o = idx / 72, k = idx - o * 72;
        lds_wv0h[idx] = (_Float16)((k < 62) ? wv0g[o * 62 + k] : 0.f);
    }
    const float* wv1g = wvb + 15872 + b * 256;
    const float* wv2g = wvb + 15872 + 4096 + b * 256;
    const float* wv3g = wvb + 15872 + 8192 + b * 256;
    for (int idx = threadIdx.x; idx < 3 * 16 * 40; idx += 512) {
        int li = idx / 640, rest = idx - li * 640;
        int o = rest / 40, k = rest - o * 40;
        const float* src = (li == 0) ? wv1g : (li == 1) ? wv2g : wv3g;
        lds_wvh[idx] = (_Float16)((k < 16) ? src[o * 16 + k] : 0.f);
    }
    if (threadIdx.x < 112) {
        int o = threadIdx.x;
        lds_b1[o] = (o < 100) ? b1[o] : 0.f;
        lds_b2[o] = (o < 100) ? b2[o] : 0.f;
        lds_w3[o] = (o < 100) ? w3[o] : 0.f;
    }
    if (threadIdx.x >= 128 && threadIdx.x < 192) {
        int t = threadIdx.x - 128;
        int li = t >> 4, o = t & 15;
        const float* mbp = (li == 0) ? mb0 : (li == 1) ? mb1 : (li == 2) ? mb2 : mb3;
        lds_mb[t] = mbp[o];
    }
    __syncthreads();

    const int l    = threadIdx.x & 63;
    const int w    = threadIdx.x >> 6;
    const int lrow = l & 15;   // point-col (B) / out-row (A,C)
    const int lkg  = l >> 4;   // k-group
    _Float16* bwave = lds_bounce + w * (16 * 40);
    const int pbase = w * 64;
    const float b3v = b3[0];
    const int ptg0 = (p0 + pbase) >> 4;

    #pragma unroll 1
    for (int pt = 0; pt < 4; ++pt) {
        const int pcol = p0 + pbase + pt * 16 + lrow;

        // ---- posenc B-frags (single f16) ----
        half8 pb0, pb1;
        if (PRE) {
            size_t base = (size_t)(ptg0 + pt) * 1024 + (size_t)lkg * 128 + (size_t)lrow * 8;
            pb0 = *(const half8*)(peh + base);
            pb1 = *(const half8*)(peh + base + 512);
        } else {
            const float x0 = xg[2 * pcol], x1 = xg[2 * pcol + 1];
            #pragma unroll
            for (int j = 0; j < 8; ++j) {
                int idx2 = 8 * lkg + j - 2;
                int s = idx2 >> 1;
                float sc = __uint_as_float((unsigned)(127 + s) << 23);
                float xa = (idx2 & 1) ? x1 : x0;
                float v = sinf(xa * sc);
                if (lkg == 0 && j == 0) v = x0;
                if (lkg == 0 && j == 1) v = x1;
                pb0[j] = (_Float16)v;
            }
            #pragma unroll
            for (int j = 0; j < 8; ++j) {
                int t = 8 * lkg + j;
                int s = t >> 1;
                float sc = __uint_as_float((unsigned)(127 + s) << 23);
                float xa = (t & 1) ? x1 : x0;
                float v = sinf(fmaf(xa, sc, PIO2F));
                if (t >= 30) v = 0.f;
                pb1[j] = (_Float16)v;
            }
        }

        // ---- layer 0: K=64 (2 k-steps, hi only) ----
        f32x4 acc = *(const f32x4*)(lds_mb + lkg * 4);
        {
            half8 a0 = *(const half8*)(lds_wv0h + lrow * 72 + lkg * 8);
            acc = mfma16h(a0, pb0, acc);
            a0 = *(const half8*)(lds_wv0h + lrow * 72 + 32 + lkg * 8);
            acc = mfma16h(a0, pb1, acc);
        }

        // ---- layers 1..3: K=16 real (rows 16..31 zero in LDS) ----
        #pragma unroll
        for (int li = 0; li < 3; ++li) {
            half4 hv;
            #pragma unroll
            for (int r = 0; r < 4; ++r) hv[r] = (_Float16)silu_f(acc[r]);
            lds_fence();                                   // prev read -> this write
            *(half4*)(bwave + lrow * 40 + lkg * 4) = hv;
            lds_fence();                                   // write -> cross-lane read
            half8 f = *(const half8*)(bwave + lrow * 40 + (lkg & 1) * 8);
            acc = *(const f32x4*)(lds_mb + (li + 1) * 16 + lkg * 4);
            half8 ah = *(const half8*)(lds_wvh + (li * 16 + lrow) * 40 + lkg * 8);
            acc = mfma16h(ah, f, acc);
        }
        // hb = silu(layer3) -> bounce -> hb frag
        {
            half4 hv;
            #pragma unroll
            for (int r = 0; r < 4; ++r) hv[r] = (_Float16)silu_f(acc[r]);
            lds_fence();
            *(half4*)(bwave + lrow * 40 + lkg * 4) = hv;
            lds_fence();
        }
        half8 hbf = *(const half8*)(bwave + lrow * 40 + (lkg & 1) * 8);

        // ---- w1 interleaved with w2 per k-slice; a2[7] accumulates across ks ----
        f32x4 a2[7];
        #pragma unroll
        for (int f2 = 0; f2 < 7; ++f2)
            a2[f2] = *(const f32x4*)(lds_b2 + f2 * 16 + lkg * 4);
        #pragma unroll
        for (int ks = 0; ks < 4; ++ks) {
            lds_fence();                                   // prev h2 read -> these writes
            #pragma unroll
            for (int lf = 0; lf < 2; ++lf) {
                const int fmt = 2 * ks + lf;
                if (fmt < 7) {
                    f32x4 a1 = *(const f32x4*)(lds_b1 + fmt * 16 + lkg * 4);
                    half8 ah = *(const half8*)(lds_w1h + (fmt * 16 + lrow) * 40 + lkg * 8);
                    a1 = mfma16h(ah, hbf, a1);
                    half4 hv;
                    #pragma unroll
                    for (int r = 0; r < 4; ++r) hv[r] = (_Float16)silu_f(a1[r]);
                    *(half4*)(bwave + lrow * 40 + lf * 16 + lkg * 4) = hv;
                }
            }
            lds_fence();                                   // writes -> cross-lane read
            half8 h2f = *(const half8*)(bwave + lrow * 40 + lkg * 8);
            const int kb = ks * 32 + lkg * 8;
            // ks==3: clamp into the zero-pad region (cols 104..119 are 0)
            const int kba = (ks == 3) ? ((kb > 112) ? 112 : kb) : kb;
            #pragma unroll
            for (int f2 = 0; f2 < 7; ++f2) {
                half8 ah = *(const half8*)(lds_w2h + (f2 * 16 + lrow) * 120 + kba);
                half8 al = *(const half8*)(lds_w2l + (f2 * 16 + lrow) * 120 + kba);
                a2[f2] = mfma16h(ah, h2f, a2[f2]);
                a2[f2] = mfma16h(al, h2f, a2[f2]);
            }
        }

        // ---- fused silu/w3 epilogue + cross-lane-group reduce ----
        float outv = 0.f;
        #pragma unroll
        for (int f2 = 0; f2 < 7; ++f2) {
            f32x4 w3v = *(const f32x4*)(lds_w3 + f2 * 16 + lkg * 4);
            #pragma unroll
            for (int r = 0; r < 4; ++r)
                outv = fmaf(silu_f(a2[f2][r]), w3v[r], outv);
        }
        outv += __shfl_xor(outv, 16, 64);
        outv += __shfl_xor(outv, 32, 64);
        if (l < 16)
            out[(size_t)b * N_PTS + pcol] = outv + b3v;
    }
}

// ---------------- launcher ----------------
extern "C" void kernel_launch(void* const* d_in, const int* in_sizes, int n_in,
                              void* d_out, int out_size, void* d_ws, size_t ws_size,
                              hipStream_t stream) {
    const float* x = (const float*)d_in[0];
    const float* latent = (const float*)d_in[1];
    const float *pw[4], *pb[4], *lnw[4], *lnb[4], *mb[4];
    for (int l = 0; l < 4; l++) {
        pw[l]  = (const float*)d_in[2 + 5 * l];
        pb[l]  = (const float*)d_in[3 + 5 * l];
        lnw[l] = (const float*)d_in[4 + 5 * l];
        lnb[l] = (const float*)d_in[5 + 5 * l];
        mb[l]  = (const float*)d_in[6 + 5 * l];
    }
    const float* w1 = (const float*)d_in[22];
    const float* b1 = (const float*)d_in[23];
    const float* w2 = (const float*)d_in[24];
    const float* b2 = (const float*)d_in[25];
    const float* w3 = (const float*)d_in[26];
    const float* b3 = (const float*)d_in[27];

    float* wvb = (float*)d_ws;                            // 28160 f32 = 112640 B
    _Float16* peh = (_Float16*)((char*)d_ws + 112640);    // 4 MB
    const size_t WS_NEED = 112640 + (size_t)N_PTS * 64 * sizeof(_Float16);
    bool pre = ws_size >= WS_NEED;

    wv_kernel<<<1024, 64, 0, stream>>>(latent,
        pw[0], pb[0], lnw[0], lnb[0],
        pw[1], pb[1], lnw[1], lnb[1],
        pw[2], pb[2], lnw[2], lnb[2],
        pw[3], pb[3], lnw[3], lnb[3],
        wvb);

    if (pre) {
        posenc_pre<<<N_PTS / 256, 256, 0, stream>>>(x, peh);
        hipFuncSetAttribute((const void*)mfma_kernel<true>,
                            hipFuncAttributeMaxDynamicSharedMemorySize, LDS_TOTAL);
        mfma_kernel<true><<<BATCH * (N_PTS / 512), 512, LDS_TOTAL, stream>>>(
            x, peh, wvb, mb[0], mb[1], mb[2], mb[3],
            w1, b1, w2, b2, w3, b3, (float*)d_out);
    } else {
        hipFuncSetAttribute((const void*)mfma_kernel<false>,
                            hipFuncAttributeMaxDynamicSharedMemorySize, LDS_TOTAL);
        mfma_kernel<false><<<BATCH * (N_PTS / 512), 512, LDS_TOTAL, stream>>>(
            x, peh, wvb, mb[0], mb[1], mb[2], mb[3],
            w1, b1, w2, b2, w3, b3, (float*)d_out);
    }
}

// Round 15
// 75.698 us; speedup vs baseline: 3.8954x; 1.1932x over previous
//
#include <hip/hip_runtime.h>

#define N_PTS 32768
#define BATCH 16
#define PIO2F 1.5707963705062866f

// ---------------- types / helpers ----------------
typedef __attribute__((ext_vector_type(8))) _Float16 half8;
typedef __attribute__((ext_vector_type(4))) _Float16 half4;
typedef __attribute__((ext_vector_type(4))) float f32x4;

__device__ __forceinline__ float silu_f(float v) {
    return v * __builtin_amdgcn_rcpf(1.0f + __expf(-v));
}

__device__ __forceinline__ float wave_sum(float v) {
    #pragma unroll
    for (int off = 1; off < 64; off <<= 1) v += __shfl_xor(v, off, 64);
    return v;
}

// Free compile-time fence: makes intra-wave cross-lane LDS handoff defined
// (R11 lesson: without it the scheduler reorders ds_write vs cross-lane ds_read).
__device__ __forceinline__ void lds_fence() {
    asm volatile("" ::: "memory");
#if __has_builtin(__builtin_amdgcn_wave_barrier)
    __builtin_amdgcn_wave_barrier();
#else
    __builtin_amdgcn_sched_barrier(0);
#endif
    asm volatile("" ::: "memory");
}

__device__ __forceinline__ f32x4 mfma16h(half8 a, half8 b, f32x4 c) {
    return __builtin_amdgcn_mfma_f32_16x16x32_f16(a, b, c, 0, 0, 0);
}

// ---------------- kernel 1: hyper-weights wv (latent einsum + LN) ----------------
__global__ void wv_kernel(
    const float* __restrict__ latent,
    const float* __restrict__ pw0, const float* __restrict__ pb0,
    const float* __restrict__ lnw0, const float* __restrict__ lnb0,
    const float* __restrict__ pw1, const float* __restrict__ pb1,
    const float* __restrict__ lnw1, const float* __restrict__ lnb1,
    const float* __restrict__ pw2, const float* __restrict__ pb2,
    const float* __restrict__ lnw2, const float* __restrict__ lnb2,
    const float* __restrict__ pw3, const float* __restrict__ pb3,
    const float* __restrict__ lnw3, const float* __restrict__ lnb3,
    float* __restrict__ wvb) {
    int blk = blockIdx.x;
    int l = blk >> 8;
    int rest = blk & 255;
    int b = rest >> 4, o = rest & 15;
    int c = threadIdx.x;

    const float *pw, *pb, *lnw, *lnb;
    float* outp;
    int ch;
    switch (l) {
        case 0:  pw = pw0; pb = pb0; lnw = lnw0; lnb = lnb0; outp = wvb;                 ch = 62; break;
        case 1:  pw = pw1; pb = pb1; lnw = lnw1; lnb = lnb1; outp = wvb + 15872;         ch = 16; break;
        case 2:  pw = pw2; pb = pb2; lnw = lnw2; lnb = lnb2; outp = wvb + 15872 + 4096;  ch = 16; break;
        default: pw = pw3; pb = pb3; lnw = lnw3; lnb = lnb3; outp = wvb + 15872 + 8192;  ch = 16; break;
    }
    const float* lat = latent + ((size_t)(b * 64 + l * 16 + o)) * 64;
    float dot = 0.f;
    if (c < ch) {
        const float* pr = pw + ((size_t)(o * ch + c)) * 64;
        #pragma unroll
        for (int d0 = 0; d0 < 64; d0++) dot += lat[d0] * pr[d0];
    }
    float act = (c < ch) ? dot : 0.f;
    float mu = wave_sum(act) * (1.0f / ch);
    float diff = (c < ch) ? (dot - mu) : 0.f;
    float var = wave_sum(diff * diff) * (1.0f / ch);
    float norm = diff * rsqrtf(var + 1e-5f);
    if (c < ch) outp[(size_t)(b * 16 + o) * ch + c] = norm * lnw[c] + lnb[c] + pb[o * ch + c];
}

// ---------------- kernel 1b: posenc precompute, single-f16 in frag-chunk layout ----
__global__ __launch_bounds__(256) void posenc_pre(
    const float* __restrict__ xg, _Float16* __restrict__ peh) {
    int p = blockIdx.x * 256 + threadIdx.x;
    float x0 = xg[2 * p], x1 = xg[2 * p + 1];
    size_t pbs = (size_t)(p >> 4) * 1024 + (size_t)(p & 15) * 8;
    #pragma unroll
    for (int c = 0; c < 8; ++c) {
        half8 hv;
        #pragma unroll
        for (int j = 0; j < 8; ++j) {
            float v;
            if (c < 4) {
                int f = 8 * c + j;
                int idx2 = f - 2;
                int s = idx2 >> 1;
                float sc = __uint_as_float((unsigned)(127 + s) << 23);
                float xa = (idx2 & 1) ? x1 : x0;
                v = sinf(xa * sc);
                if (f == 0) v = x0;
                if (f == 1) v = x1;
            } else {
                int t = 8 * (c - 4) + j;
                int s = t >> 1;
                float sc = __uint_as_float((unsigned)(127 + s) << 23);
                float xa = (t & 1) ? x1 : x0;
                v = sinf(fmaf(xa, sc, PIO2F));
                if (t >= 30) v = 0.f;
            }
            hv[j] = (_Float16)v;
        }
        *(half8*)(peh + pbs + c * 128) = hv;
    }
}

// ---------------- LDS layout (bytes), total 52032 -> 3 blocks/CU (24 waves) ----------------
// All K-tails ZERO-FILLED in LDS (no cndmask in hot loop).
#define BOUNCE_OFF  0            // f16 8 x [16][40]   10240
#define W2H_OFF     10240        // f16 [112][112]     25088  (cols 100..111 = 0)
#define W1H_OFF     35328        // f16 [112][40]       8960  (cols 16..39 = 0)
#define WV0H_OFF    44288        // f16 [16][72]        2304  (cols 62..71 = 0)
#define WVH_OFF     46592        // f16 [3][16][40]     3840  (cols 16..39 = 0)
#define B1_OFF      50432        // f32 [112]            448
#define B2_OFF      50880        // f32 [112]            448
#define W3_OFF      51328        // f32 [112]            448
#define MB_LDS_OFF  51776        // f32 [4][16]          256
#define LDS_TOTAL   52032

// ---------------- kernel 2: full per-point pipeline on MFMA (fp16 datapath) ----------------
// ALL weights single-term f16 (precision headroom: measured error was pinned
// at exactly 1 output-bf16 ulp = 4.88e-4 with a 3-ulp threshold). 52 KB LDS
// -> 3 blocks/CU = 6 waves/SIMD for latency hiding (R14 was dependency-bound).
template <bool PRE>
__global__ __launch_bounds__(512, 2) void mfma_kernel(
    const float* __restrict__ xg,
    const _Float16* __restrict__ peh,
    const float* __restrict__ wvb,
    const float* __restrict__ mb0, const float* __restrict__ mb1,
    const float* __restrict__ mb2, const float* __restrict__ mb3,
    const float* __restrict__ w1, const float* __restrict__ b1,
    const float* __restrict__ w2, const float* __restrict__ b2,
    const float* __restrict__ w3, const float* __restrict__ b3,
    float* __restrict__ out) {
    extern __shared__ char smem[];
    _Float16* lds_bounce = (_Float16*)(smem + BOUNCE_OFF);
    _Float16* lds_w2h    = (_Float16*)(smem + W2H_OFF);
    _Float16* lds_w1h    = (_Float16*)(smem + W1H_OFF);
    _Float16* lds_wv0h   = (_Float16*)(smem + WV0H_OFF);
    _Float16* lds_wvh    = (_Float16*)(smem + WVH_OFF);
    float*    lds_b1     = (float*)(smem + B1_OFF);
    float*    lds_b2     = (float*)(smem + B2_OFF);
    float*    lds_w3     = (float*)(smem + W3_OFF);
    float*    lds_mb     = (float*)(smem + MB_LDS_OFF);

    const int b  = blockIdx.x >> 6;
    const int p0 = (blockIdx.x & 63) * 512;

    // ---- stage weights (zero-padded K, single-term f16) ----
    for (int idx = threadIdx.x; idx < 112 * 112; idx += 512) {
        int o = idx / 112, k = idx - o * 112;
        lds_w2h[idx] = (_Float16)((o < 100 && k < 100) ? w2[o * 100 + k] : 0.f);
    }
    for (int idx = threadIdx.x; idx < 112 * 40; idx += 512) {
        int o = idx / 40, k = idx - o * 40;
        lds_w1h[idx] = (_Float16)((o < 100 && k < 16) ? w1[o * 16 + k] : 0.f);
    }
    const float* wv0g = wvb + b * 992;                 // [16][62]
    for (int idx = threadIdx.x; idx < 16 * 72; idx += 512) {
        int o = idx / 72, k = idx - o * 72;
        lds_wv0h[idx] = (_Float16)((k < 62) ? wv0g[o * 62 + k] : 0.f);
    }
    const float* wv1g = wvb + 15872 + b * 256;
    const float* wv2g = wvb + 15872 + 4096 + b * 256;
    const float* wv3g = wvb + 15872 + 8192 + b * 256;
    for (int idx = threadIdx.x; idx < 3 * 16 * 40; idx += 512) {
        int li = idx / 640, rest = idx - li * 640;
        int o = rest / 40, k = rest - o * 40;
        const float* src = (li == 0) ? wv1g : (li == 1) ? wv2g : wv3g;
        lds_wvh[idx] = (_Float16)((k < 16) ? src[o * 16 + k] : 0.f);
    }
    if (threadIdx.x < 112) {
        int o = threadIdx.x;
        lds_b1[o] = (o < 100) ? b1[o] : 0.f;
        lds_b2[o] = (o < 100) ? b2[o] : 0.f;
        lds_w3[o] = (o < 100) ? w3[o] : 0.f;
    }
    if (threadIdx.x >= 128 && threadIdx.x < 192) {
        int t = threadIdx.x - 128;
        int li = t >> 4, o = t & 15;
        const float* mbp = (li == 0) ? mb0 : (li == 1) ? mb1 : (li == 2) ? mb2 : mb3;
        lds_mb[t] = mbp[o];
    }
    __syncthreads();

    const int l    = threadIdx.x & 63;
    const int w    = threadIdx.x >> 6;
    const int lrow = l & 15;   // point-col (B) / out-row (A,C)
    const int lkg  = l >> 4;   // k-group
    _Float16* bwave = lds_bounce + w * (16 * 40);
    const int pbase = w * 64;
    const float b3v = b3[0];
    const int ptg0 = (p0 + pbase) >> 4;

    #pragma unroll 1
    for (int pt = 0; pt < 4; ++pt) {
        const int pcol = p0 + pbase + pt * 16 + lrow;

        // ---- posenc B-frags (single f16) ----
        half8 pb0, pb1;
        if (PRE) {
            size_t base = (size_t)(ptg0 + pt) * 1024 + (size_t)lkg * 128 + (size_t)lrow * 8;
            pb0 = *(const half8*)(peh + base);
            pb1 = *(const half8*)(peh + base + 512);
        } else {
            const float x0 = xg[2 * pcol], x1 = xg[2 * pcol + 1];
            #pragma unroll
            for (int j = 0; j < 8; ++j) {
                int idx2 = 8 * lkg + j - 2;
                int s = idx2 >> 1;
                float sc = __uint_as_float((unsigned)(127 + s) << 23);
                float xa = (idx2 & 1) ? x1 : x0;
                float v = sinf(xa * sc);
                if (lkg == 0 && j == 0) v = x0;
                if (lkg == 0 && j == 1) v = x1;
                pb0[j] = (_Float16)v;
            }
            #pragma unroll
            for (int j = 0; j < 8; ++j) {
                int t = 8 * lkg + j;
                int s = t >> 1;
                float sc = __uint_as_float((unsigned)(127 + s) << 23);
                float xa = (t & 1) ? x1 : x0;
                float v = sinf(fmaf(xa, sc, PIO2F));
                if (t >= 30) v = 0.f;
                pb1[j] = (_Float16)v;
            }
        }

        // ---- layer 0: K=64 (2 k-steps) ----
        f32x4 acc = *(const f32x4*)(lds_mb + lkg * 4);
        {
            half8 a0 = *(const half8*)(lds_wv0h + lrow * 72 + lkg * 8);
            acc = mfma16h(a0, pb0, acc);
            a0 = *(const half8*)(lds_wv0h + lrow * 72 + 32 + lkg * 8);
            acc = mfma16h(a0, pb1, acc);
        }

        // ---- layers 1..3: K=16 real (rows 16..31 zero in LDS) ----
        #pragma unroll
        for (int li = 0; li < 3; ++li) {
            half4 hv;
            #pragma unroll
            for (int r = 0; r < 4; ++r) hv[r] = (_Float16)silu_f(acc[r]);
            lds_fence();                                   // prev read -> this write
            *(half4*)(bwave + lrow * 40 + lkg * 4) = hv;
            lds_fence();                                   // write -> cross-lane read
            half8 f = *(const half8*)(bwave + lrow * 40 + (lkg & 1) * 8);
            acc = *(const f32x4*)(lds_mb + (li + 1) * 16 + lkg * 4);
            half8 ah = *(const half8*)(lds_wvh + (li * 16 + lrow) * 40 + lkg * 8);
            acc = mfma16h(ah, f, acc);
        }
        // hb = silu(layer3) -> bounce -> hb frag
        {
            half4 hv;
            #pragma unroll
            for (int r = 0; r < 4; ++r) hv[r] = (_Float16)silu_f(acc[r]);
            lds_fence();
            *(half4*)(bwave + lrow * 40 + lkg * 4) = hv;
            lds_fence();
        }
        half8 hbf = *(const half8*)(bwave + lrow * 40 + (lkg & 1) * 8);

        // ---- w1 interleaved with w2 per k-slice; a2[7] accumulates across ks ----
        f32x4 a2[7];
        #pragma unroll
        for (int f2 = 0; f2 < 7; ++f2)
            a2[f2] = *(const f32x4*)(lds_b2 + f2 * 16 + lkg * 4);
        #pragma unroll
        for (int ks = 0; ks < 4; ++ks) {
            lds_fence();                                   // prev h2 read -> these writes
            #pragma unroll
            for (int lf = 0; lf < 2; ++lf) {
                const int fmt = 2 * ks + lf;
                if (fmt < 7) {
                    f32x4 a1 = *(const f32x4*)(lds_b1 + fmt * 16 + lkg * 4);
                    half8 ah = *(const half8*)(lds_w1h + (fmt * 16 + lrow) * 40 + lkg * 8);
                    a1 = mfma16h(ah, hbf, a1);
                    half4 hv;
                    #pragma unroll
                    for (int r = 0; r < 4; ++r) hv[r] = (_Float16)silu_f(a1[r]);
                    *(half4*)(bwave + lrow * 40 + lf * 16 + lkg * 4) = hv;
                }
            }
            lds_fence();                                   // writes -> cross-lane read
            half8 h2f = *(const half8*)(bwave + lrow * 40 + lkg * 8);
            const int kb = ks * 32 + lkg * 8;
            // ks==3: clamp into the zero-pad region (cols 100..111 are 0)
            const int kba = (ks == 3) ? ((kb > 104) ? 104 : kb) : kb;
            #pragma unroll
            for (int f2 = 0; f2 < 7; ++f2) {
                half8 ah = *(const half8*)(lds_w2h + (f2 * 16 + lrow) * 112 + kba);
                a2[f2] = mfma16h(ah, h2f, a2[f2]);
            }
        }

        // ---- fused silu/w3 epilogue + cross-lane-group reduce ----
        float outv = 0.f;
        #pragma unroll
        for (int f2 = 0; f2 < 7; ++f2) {
            f32x4 w3v = *(const f32x4*)(lds_w3 + f2 * 16 + lkg * 4);
            #pragma unroll
            for (int r = 0; r < 4; ++r)
                outv = fmaf(silu_f(a2[f2][r]), w3v[r], outv);
        }
        outv += __shfl_xor(outv, 16, 64);
        outv += __shfl_xor(outv, 32, 64);
        if (l < 16)
            out[(size_t)b * N_PTS + pcol] = outv + b3v;
    }
}

// ---------------- launcher ----------------
extern "C" void kernel_launch(void* const* d_in, const int* in_sizes, int n_in,
                              void* d_out, int out_size, void* d_ws, size_t ws_size,
                              hipStream_t stream) {
    const float* x = (const float*)d_in[0];
    const float* latent = (const float*)d_in[1];
    const float *pw[4], *pb[4], *lnw[4], *lnb[4], *mb[4];
    for (int l = 0; l < 4; l++) {
        pw[l]  = (const float*)d_in[2 + 5 * l];
        pb[l]  = (const float*)d_in[3 + 5 * l];
        lnw[l] = (const float*)d_in[4 + 5 * l];
        lnb[l] = (const float*)d_in[5 + 5 * l];
        mb[l]  = (const float*)d_in[6 + 5 * l];
    }
    const float* w1 = (const float*)d_in[22];
    const float* b1 = (const float*)d_in[23];
    const float* w2 = (const float*)d_in[24];
    const float* b2 = (const float*)d_in[25];
    const float* w3 = (const float*)d_in[26];
    const float* b3 = (const float*)d_in[27];

    float* wvb = (float*)d_ws;                            // 28160 f32 = 112640 B
    _Float16* peh = (_Float16*)((char*)d_ws + 112640);    // 4 MB
    const size_t WS_NEED = 112640 + (size_t)N_PTS * 64 * sizeof(_Float16);
    bool pre = ws_size >= WS_NEED;

    wv_kernel<<<1024, 64, 0, stream>>>(latent,
        pw[0], pb[0], lnw[0], lnb[0],
        pw[1], pb[1], lnw[1], lnb[1],
        pw[2], pb[2], lnw[2], lnb[2],
        pw[3], pb[3], lnw[3], lnb[3],
        wvb);

    if (pre) {
        posenc_pre<<<N_PTS / 256, 256, 0, stream>>>(x, peh);
        hipFuncSetAttribute((const void*)mfma_kernel<true>,
                            hipFuncAttributeMaxDynamicSharedMemorySize, LDS_TOTAL);
        mfma_kernel<true><<<BATCH * (N_PTS / 512), 512, LDS_TOTAL, stream>>>(
            x, peh, wvb, mb[0], mb[1], mb[2], mb[3],
            w1, b1, w2, b2, w3, b3, (float*)d_out);
    } else {
        hipFuncSetAttribute((const void*)mfma_kernel<false>,
                            hipFuncAttributeMaxDynamicSharedMemorySize, LDS_TOTAL);
        mfma_kernel<false><<<BATCH * (N_PTS / 512), 512, LDS_TOTAL, stream>>>(
            x, peh, wvb, mb[0], mb[1], mb[2], mb[3],
            w1, b1, w2, b2, w3, b3, (float*)d_out);
    }
}